// Round 2
// baseline (301.459 us; speedup 1.0000x reference)
//
#include <hip/hip_runtime.h>

typedef unsigned short u16;
typedef __bf16 bf16x8 __attribute__((ext_vector_type(8)));
typedef float f32x4 __attribute__((ext_vector_type(4)));

__device__ inline u16 f2bf(float f) {
    union { float f; unsigned int u; } a; a.f = f;
    unsigned int u = a.u + 0x7fffu + ((a.u >> 16) & 1u);
    return (u16)(u >> 16);
}

// -------- transpose + cast: out_bf16[n][k] = in_f32[k][n] --------
__global__ __launch_bounds__(256) void transpose_f32_bf16(
    const float* __restrict__ in, u16* __restrict__ out, int K, int N)
{
    __shared__ u16 tile[32][33];
    int n0 = blockIdx.x * 32, k0 = blockIdx.y * 32;
    int tx = threadIdx.x & 31, ty = threadIdx.x >> 5;
    #pragma unroll
    for (int r = ty; r < 32; r += 8)
        tile[r][tx] = f2bf(in[(size_t)(k0 + r) * N + n0 + tx]);
    __syncthreads();
    #pragma unroll
    for (int r = ty; r < 32; r += 8)
        out[(size_t)(n0 + r) * K + k0 + tx] = tile[tx][r];
}

// -------- QKV GEMM: A fp32 [8192][768], Bt bf16 [2304][768] --------
// scatter: Q (*0.125) -> q_out [b,h,n,64]; K -> k_out; V -> v_out (bf16)
__global__ __launch_bounds__(256) void gemm_qkv(
    const float* __restrict__ A, const u16* __restrict__ Bt,
    u16* __restrict__ q_out, u16* __restrict__ k_out, u16* __restrict__ v_out)
{
    const int K = 768;
    __shared__ __align__(16) u16 As[128][40];
    __shared__ __align__(16) u16 Bs[128][40];

    int tid = threadIdx.x;
    int lane = tid & 63, wave = tid >> 6;
    int quad = lane >> 4, l16 = lane & 15;
    int wm = wave >> 1, wn = wave & 1;
    int m0 = blockIdx.y * 128, n0 = blockIdx.x * 128;

    f32x4 acc[4][4];
    #pragma unroll
    for (int i = 0; i < 4; i++)
        #pragma unroll
        for (int j = 0; j < 4; j++) acc[i][j] = (f32x4){0.f, 0.f, 0.f, 0.f};

    for (int kt = 0; kt < K; kt += 32) {
        #pragma unroll
        for (int it = 0; it < 2; ++it) {
            int e = it * 256 + tid;
            int row = e >> 2, c8 = (e & 3) * 8;
            // A: fp32 -> bf16 on the fly
            float4 f0 = *(const float4*)&A[(size_t)(m0 + row) * K + kt + c8];
            float4 f1 = *(const float4*)&A[(size_t)(m0 + row) * K + kt + c8 + 4];
            u16 tmp[8];
            tmp[0]=f2bf(f0.x); tmp[1]=f2bf(f0.y); tmp[2]=f2bf(f0.z); tmp[3]=f2bf(f0.w);
            tmp[4]=f2bf(f1.x); tmp[5]=f2bf(f1.y); tmp[6]=f2bf(f1.z); tmp[7]=f2bf(f1.w);
            *(uint4*)&As[row][c8] = *(const uint4*)tmp;
            *(uint4*)&Bs[row][c8] = *(const uint4*)&Bt[(size_t)(n0 + row) * K + kt + c8];
        }
        __syncthreads();
        bf16x8 af[4], bfr[4];
        #pragma unroll
        for (int i = 0; i < 4; i++) af[i]  = *(const bf16x8*)&As[wm * 64 + i * 16 + l16][quad * 8];
        #pragma unroll
        for (int j = 0; j < 4; j++) bfr[j] = *(const bf16x8*)&Bs[wn * 64 + j * 16 + l16][quad * 8];
        #pragma unroll
        for (int i = 0; i < 4; i++)
            #pragma unroll
            for (int j = 0; j < 4; j++)
                acc[i][j] = __builtin_amdgcn_mfma_f32_16x16x32_bf16(af[i], bfr[j], acc[i][j], 0, 0, 0);
        __syncthreads();
    }

    // C/D layout: col = lane&15, row = quad*4 + reg
    #pragma unroll
    for (int i = 0; i < 4; i++) {
        int mbase = m0 + wm * 64 + i * 16 + quad * 4;
        #pragma unroll
        for (int j = 0; j < 4; j++) {
            int n = n0 + wn * 64 + j * 16 + l16;
            int part  = n >= 1536 ? 2 : (n >= 768 ? 1 : 0);
            int inner = n - part * 768;
            int h = inner >> 6, dd = inner & 63;
            #pragma unroll
            for (int r = 0; r < 4; r++) {
                int m = mbase + r;
                int b = m >> 10, npos = m & 1023;
                size_t idx = ((size_t)((b * 12 + h) * 1024 + npos)) * 64 + dd;
                float v = acc[i][j][r];
                if      (part == 0) q_out[idx] = f2bf(v * 0.125f);  // fold 1/sqrt(64)
                else if (part == 1) k_out[idx] = f2bf(v);
                else                v_out[idx] = f2bf(v);
            }
        }
    }
}

// -------- flash attention, in-place O over Q: block = (b,h) x 64 q-rows --------
__global__ __launch_bounds__(256) void attn64(
    u16* __restrict__ QO, const u16* __restrict__ Kg, const u16* __restrict__ V)
{
    __shared__ __align__(16) u16 Ks[64][72];
    __shared__ __align__(16) u16 Vt[64][72];       // [d][kv]
    __shared__ __align__(16) u16 Sp[4][16][72];    // per-wave P round-trip

    int tid = threadIdx.x;
    int lane = tid & 63, wave = tid >> 6;
    int quad = lane >> 4, l16 = lane & 15;
    int bh = blockIdx.y;
    int q0 = blockIdx.x * 64;
    const size_t head_base = (size_t)bh * 1024 * 64;

    // Q fragments (A-layout: m = l16, k = quad*8+j); Q pre-scaled by 0.125
    int qrow = q0 + wave * 16 + l16;
    bf16x8 qf0 = *(const bf16x8*)&QO[head_base + (size_t)qrow * 64 + quad * 8];
    bf16x8 qf1 = *(const bf16x8*)&QO[head_base + (size_t)qrow * 64 + 32 + quad * 8];

    f32x4 Oacc[4];
    #pragma unroll
    for (int nt = 0; nt < 4; nt++) Oacc[nt] = (f32x4){0.f, 0.f, 0.f, 0.f};
    float m_run[4], l_run[4];
    #pragma unroll
    for (int r = 0; r < 4; r++) { m_run[r] = -1e30f; l_run[r] = 0.f; }

    for (int j0 = 0; j0 < 1024; j0 += 64) {
        #pragma unroll
        for (int it = 0; it < 2; ++it) {
            int e = it * 256 + tid;
            int row = e >> 3, c8 = (e & 7) * 8;
            *(uint4*)&Ks[row][c8] = *(const uint4*)&Kg[head_base + (size_t)(j0 + row) * 64 + c8];
            union { uint4 v4; u16 s[8]; } tv;
            tv.v4 = *(const uint4*)&V[head_base + (size_t)(j0 + row) * 64 + c8];
            #pragma unroll
            for (int jj = 0; jj < 8; jj++) Vt[c8 + jj][row] = tv.s[jj];
        }
        __syncthreads();

        // S = Q K^T  (D: row=quad*4+reg (q-local), col=l16 (kv-local))
        f32x4 s4[4];
        #pragma unroll
        for (int nt = 0; nt < 4; nt++) {
            bf16x8 kf0 = *(const bf16x8*)&Ks[nt * 16 + l16][quad * 8];
            bf16x8 kf1 = *(const bf16x8*)&Ks[nt * 16 + l16][32 + quad * 8];
            f32x4 s = (f32x4){0.f, 0.f, 0.f, 0.f};
            s = __builtin_amdgcn_mfma_f32_16x16x32_bf16(qf0, kf0, s, 0, 0, 0);
            s = __builtin_amdgcn_mfma_f32_16x16x32_bf16(qf1, kf1, s, 0, 0, 0);
            s4[nt] = s;
        }

        // online softmax; row quad*4+r spans the 16 lanes of this quad-group
        #pragma unroll
        for (int r = 0; r < 4; r++) {
            float mx = fmaxf(fmaxf(s4[0][r], s4[1][r]), fmaxf(s4[2][r], s4[3][r]));
            mx = fmaxf(mx, __shfl_xor(mx, 1));
            mx = fmaxf(mx, __shfl_xor(mx, 2));
            mx = fmaxf(mx, __shfl_xor(mx, 4));
            mx = fmaxf(mx, __shfl_xor(mx, 8));
            float m_new = fmaxf(m_run[r], mx);
            float alpha = __expf(m_run[r] - m_new);
            float sum = 0.f;
            #pragma unroll
            for (int nt = 0; nt < 4; nt++) {
                float p = __expf(s4[nt][r] - m_new);
                s4[nt][r] = p;
                sum += p;
            }
            sum += __shfl_xor(sum, 1);
            sum += __shfl_xor(sum, 2);
            sum += __shfl_xor(sum, 4);
            sum += __shfl_xor(sum, 8);
            l_run[r] = l_run[r] * alpha + sum;
            m_run[r] = m_new;
            #pragma unroll
            for (int nt = 0; nt < 4; nt++) Oacc[nt][r] *= alpha;
        }

        // P: C-layout -> LDS -> A-layout
        #pragma unroll
        for (int nt = 0; nt < 4; nt++)
            #pragma unroll
            for (int r = 0; r < 4; r++)
                Sp[wave][quad * 4 + r][nt * 16 + l16] = f2bf(s4[nt][r]);
        __syncthreads();

        bf16x8 pf0 = *(const bf16x8*)&Sp[wave][l16][quad * 8];
        bf16x8 pf1 = *(const bf16x8*)&Sp[wave][l16][32 + quad * 8];
        #pragma unroll
        for (int nt = 0; nt < 4; nt++) {
            bf16x8 vf0 = *(const bf16x8*)&Vt[nt * 16 + l16][quad * 8];
            bf16x8 vf1 = *(const bf16x8*)&Vt[nt * 16 + l16][32 + quad * 8];
            Oacc[nt] = __builtin_amdgcn_mfma_f32_16x16x32_bf16(pf0, vf0, Oacc[nt], 0, 0, 0);
            Oacc[nt] = __builtin_amdgcn_mfma_f32_16x16x32_bf16(pf1, vf1, Oacc[nt], 0, 0, 0);
        }
        __syncthreads();
    }

    // write O in-place over this block's own Q rows ([b,h,n,d] layout)
    #pragma unroll
    for (int nt = 0; nt < 4; nt++)
        #pragma unroll
        for (int r = 0; r < 4; r++) {
            int row = q0 + wave * 16 + quad * 4 + r;
            int col = nt * 16 + l16;
            QO[head_base + (size_t)row * 64 + col] = f2bf(Oacc[nt][r] / l_run[r]);
        }
}

// -------- out-proj GEMM: A = O bf16 gathered [b,h,n,d], Bt bf16 [768][768] --------
__global__ __launch_bounds__(256) void gemm_out(
    const u16* __restrict__ Qg, const u16* __restrict__ Bt,
    const float* __restrict__ bias, float* __restrict__ out)
{
    const int K = 768;
    __shared__ __align__(16) u16 As[128][40];
    __shared__ __align__(16) u16 Bs[128][40];

    int tid = threadIdx.x;
    int lane = tid & 63, wave = tid >> 6;
    int quad = lane >> 4, l16 = lane & 15;
    int wm = wave >> 1, wn = wave & 1;
    int m0 = blockIdx.y * 128, n0 = blockIdx.x * 128;

    f32x4 acc[4][4];
    #pragma unroll
    for (int i = 0; i < 4; i++)
        #pragma unroll
        for (int j = 0; j < 4; j++) acc[i][j] = (f32x4){0.f, 0.f, 0.f, 0.f};

    for (int kt = 0; kt < K; kt += 32) {
        #pragma unroll
        for (int it = 0; it < 2; ++it) {
            int e = it * 256 + tid;
            int row = e >> 2, c8 = (e & 3) * 8;
            int m = m0 + row, b = m >> 10, npos = m & 1023;
            int k = kt + c8, h = k >> 6, dd = k & 63;
            *(uint4*)&As[row][c8] =
                *(const uint4*)&Qg[(((size_t)(b * 12 + h) * 1024 + npos) << 6) + dd];
            *(uint4*)&Bs[row][c8] = *(const uint4*)&Bt[(size_t)(n0 + row) * K + kt + c8];
        }
        __syncthreads();
        bf16x8 af[4], bfr[4];
        #pragma unroll
        for (int i = 0; i < 4; i++) af[i]  = *(const bf16x8*)&As[wm * 64 + i * 16 + l16][quad * 8];
        #pragma unroll
        for (int j = 0; j < 4; j++) bfr[j] = *(const bf16x8*)&Bs[wn * 64 + j * 16 + l16][quad * 8];
        #pragma unroll
        for (int i = 0; i < 4; i++)
            #pragma unroll
            for (int j = 0; j < 4; j++)
                acc[i][j] = __builtin_amdgcn_mfma_f32_16x16x32_bf16(af[i], bfr[j], acc[i][j], 0, 0, 0);
        __syncthreads();
    }

    #pragma unroll
    for (int i = 0; i < 4; i++) {
        int mbase = m0 + wm * 64 + i * 16 + quad * 4;
        #pragma unroll
        for (int j = 0; j < 4; j++) {
            int n = n0 + wn * 64 + j * 16 + l16;
            float bv = bias[n];
            #pragma unroll
            for (int r = 0; r < 4; r++)
                out[(size_t)(mbase + r) * 768 + n] = acc[i][j][r] + bv;
        }
    }
}

extern "C" void kernel_launch(void* const* d_in, const int* in_sizes, int n_in,
                              void* d_out, int out_size, void* d_ws, size_t ws_size,
                              hipStream_t stream) {
    const float* x     = (const float*)d_in[0];   // [8,1024,768] f32
    const float* w_qkv = (const float*)d_in[1];   // [768,2304] f32
    const float* w_out = (const float*)d_in[2];   // [768,768] f32
    const float* b_out = (const float*)d_in[3];   // [768] f32
    float* out = (float*)d_out;                   // [8,1024,768] f32 (25,165,824 B)

    char* ws = (char*)d_ws;
    u16* wtq  = (u16*)(ws);                  // [2304][768] bf16  3,538,944 B
    u16* wto  = (u16*)(ws + 3538944);        // [768][768]  bf16  1,179,648 B
    u16* Qbuf = (u16*)(ws + 4718592);        // [8,12,1024,64] bf16 12,582,912 B -> 17.3 MB total
    // K,V live inside d_out (exactly 2 x 12,582,912 B = 25,165,824 B); fully
    // consumed by attn64 before gemm_out overwrites d_out with fp32 results.
    u16* Kbuf = (u16*)d_out;
    u16* Vbuf = (u16*)d_out + 6291456;

    transpose_f32_bf16<<<dim3(72, 24), 256, 0, stream>>>(w_qkv, wtq, 768, 2304);
    transpose_f32_bf16<<<dim3(24, 24), 256, 0, stream>>>(w_out, wto, 768, 768);
    gemm_qkv<<<dim3(18, 64), 256, 0, stream>>>(x, wtq, Qbuf, Kbuf, Vbuf);
    attn64<<<dim3(16, 96), 256, 0, stream>>>(Qbuf, Kbuf, Vbuf);
    gemm_out<<<dim3(6, 64), 256, 0, stream>>>(Qbuf, wto, b_out, out);
}

// Round 3
// 227.668 us; speedup vs baseline: 1.3241x; 1.3241x over previous
//
#include <hip/hip_runtime.h>

typedef unsigned short u16;
typedef __bf16 bf16x8 __attribute__((ext_vector_type(8)));
typedef float f32x4 __attribute__((ext_vector_type(4)));

__device__ inline u16 f2bf(float f) {
    union { float f; unsigned int u; } a; a.f = f;
    unsigned int u = a.u + 0x7fffu + ((a.u >> 16) & 1u);
    return (u16)(u >> 16);
}

// -------- x cast: f32 -> bf16, 8 elems/thread --------
__global__ __launch_bounds__(256) void cast_f32_bf16(
    const float* __restrict__ in, u16* __restrict__ out)
{
    int i = blockIdx.x * 256 + threadIdx.x;
    size_t base = (size_t)i * 8;
    float4 f0 = *(const float4*)&in[base];
    float4 f1 = *(const float4*)&in[base + 4];
    union { u16 s[8]; uint4 v; } t;
    t.s[0]=f2bf(f0.x); t.s[1]=f2bf(f0.y); t.s[2]=f2bf(f0.z); t.s[3]=f2bf(f0.w);
    t.s[4]=f2bf(f1.x); t.s[5]=f2bf(f1.y); t.s[6]=f2bf(f1.z); t.s[7]=f2bf(f1.w);
    *(uint4*)&out[base] = t.v;
}

// -------- transpose + cast: out_bf16[n][k] = in_f32[k][n] --------
__global__ __launch_bounds__(256) void transpose_f32_bf16(
    const float* __restrict__ in, u16* __restrict__ out, int K, int N)
{
    __shared__ u16 tile[32][33];
    int n0 = blockIdx.x * 32, k0 = blockIdx.y * 32;
    int tx = threadIdx.x & 31, ty = threadIdx.x >> 5;
    #pragma unroll
    for (int r = ty; r < 32; r += 8)
        tile[r][tx] = f2bf(in[(size_t)(k0 + r) * N + n0 + tx]);
    __syncthreads();
    #pragma unroll
    for (int r = ty; r < 32; r += 8)
        out[(size_t)(n0 + r) * K + k0 + tx] = tile[tx][r];
}

// -------- QKV GEMM: A bf16 [8192][768], Bt bf16 [2304][768] --------
// scatter: Q (*0.125*log2e) -> q_out [b,h,n,64]; K -> k_out; V -> v_out
__global__ __launch_bounds__(256) void gemm_qkv(
    const u16* __restrict__ A, const u16* __restrict__ Bt,
    u16* __restrict__ q_out, u16* __restrict__ k_out, u16* __restrict__ v_out)
{
    const int K = 768;
    __shared__ __align__(16) u16 As[128][40];
    __shared__ __align__(16) u16 Bs[128][40];

    int tid = threadIdx.x;
    int lane = tid & 63, wave = tid >> 6;
    int quad = lane >> 4, l16 = lane & 15;
    int wm = wave >> 1, wn = wave & 1;
    int m0 = blockIdx.y * 128, n0 = blockIdx.x * 128;

    f32x4 acc[4][4];
    #pragma unroll
    for (int i = 0; i < 4; i++)
        #pragma unroll
        for (int j = 0; j < 4; j++) acc[i][j] = (f32x4){0.f, 0.f, 0.f, 0.f};

    for (int kt = 0; kt < K; kt += 32) {
        #pragma unroll
        for (int it = 0; it < 2; ++it) {
            int e = it * 256 + tid;
            int row = e >> 2, c8 = (e & 3) * 8;
            *(uint4*)&As[row][c8] = *(const uint4*)&A [(size_t)(m0 + row) * K + kt + c8];
            *(uint4*)&Bs[row][c8] = *(const uint4*)&Bt[(size_t)(n0 + row) * K + kt + c8];
        }
        __syncthreads();
        bf16x8 af[4], bfr[4];
        #pragma unroll
        for (int i = 0; i < 4; i++) af[i]  = *(const bf16x8*)&As[wm * 64 + i * 16 + l16][quad * 8];
        #pragma unroll
        for (int j = 0; j < 4; j++) bfr[j] = *(const bf16x8*)&Bs[wn * 64 + j * 16 + l16][quad * 8];
        #pragma unroll
        for (int i = 0; i < 4; i++)
            #pragma unroll
            for (int j = 0; j < 4; j++)
                acc[i][j] = __builtin_amdgcn_mfma_f32_16x16x32_bf16(af[i], bfr[j], acc[i][j], 0, 0, 0);
        __syncthreads();
    }

    // C/D layout: col = lane&15, row = quad*4 + reg
    #pragma unroll
    for (int i = 0; i < 4; i++) {
        int mbase = m0 + wm * 64 + i * 16 + quad * 4;
        #pragma unroll
        for (int j = 0; j < 4; j++) {
            int n = n0 + wn * 64 + j * 16 + l16;
            int part  = n >= 1536 ? 2 : (n >= 768 ? 1 : 0);
            int inner = n - part * 768;
            int h = inner >> 6, dd = inner & 63;
            #pragma unroll
            for (int r = 0; r < 4; r++) {
                int m = mbase + r;
                int b = m >> 10, npos = m & 1023;
                size_t idx = ((size_t)((b * 12 + h) * 1024 + npos)) * 64 + dd;
                float v = acc[i][j][r];
                if      (part == 0) q_out[idx] = f2bf(v * 0.18033688011112042f); // /8 * log2(e)
                else if (part == 1) k_out[idx] = f2bf(v);
                else                v_out[idx] = f2bf(v);
            }
        }
    }
}

// -------- flash attention (S^T form, no max, P stays in registers) --------
// block = (b,h) x 64 q; O written in-place over Q
__global__ __launch_bounds__(256) void attn64(
    u16* __restrict__ QO, const u16* __restrict__ Kg, const u16* __restrict__ V)
{
    __shared__ __align__(16) u16 Ks[64][72];   // K natural [kv][d]
    __shared__ __align__(16) u16 Vt[64][72];   // V^T [d][kv ^ 4*(d>>3 & 7)]

    int tid = threadIdx.x;
    int lane = tid & 63, wave = tid >> 6;
    int quad = lane >> 4, l16 = lane & 15;
    int bh = blockIdx.y;
    int q0 = blockIdx.x * 64;
    const size_t head_base = (size_t)bh * 65536;

    // Q as B-operand fragment: n=q=l16(+16*wave), k=d=quad*8+j; pre-scaled by 0.125*log2e
    size_t qoff = head_base + (size_t)(q0 + wave * 16 + l16) * 64;
    bf16x8 qf0 = *(const bf16x8*)&QO[qoff + quad * 8];
    bf16x8 qf1 = *(const bf16x8*)&QO[qoff + 32 + quad * 8];

    f32x4 Oacc[4];   // O^T C-layout: d = dt*16 + quad*4 + r, q = l16
    #pragma unroll
    for (int dt = 0; dt < 4; dt++) Oacc[dt] = (f32x4){0.f, 0.f, 0.f, 0.f};
    float l_part = 0.f;

    for (int j0 = 0; j0 < 1024; j0 += 64) {
        #pragma unroll
        for (int it = 0; it < 2; ++it) {
            int e = it * 256 + tid;
            int row = e >> 3, c8 = (e & 7) * 8;   // d-group g = e&7
            *(uint4*)&Ks[row][c8] = *(const uint4*)&Kg[head_base + (size_t)(j0 + row) * 64 + c8];
            union { uint4 v4; u16 s[8]; } tv;
            tv.v4 = *(const uint4*)&V[head_base + (size_t)(j0 + row) * 64 + c8];
            int colS = row ^ (4 * (e & 7));       // XOR swizzle: spread banks across d-groups
            #pragma unroll
            for (int jj = 0; jj < 8; jj++) Vt[c8 + jj][colS] = tv.s[jj];
        }
        __syncthreads();

        // S^T = K Q^T : D[kv][q], kv = nt*16 + quad*4 + r, q = l16
        f32x4 s4[4];
        #pragma unroll
        for (int nt = 0; nt < 4; nt++) {
            bf16x8 kf0 = *(const bf16x8*)&Ks[nt * 16 + l16][quad * 8];
            bf16x8 kf1 = *(const bf16x8*)&Ks[nt * 16 + l16][32 + quad * 8];
            f32x4 s = (f32x4){0.f, 0.f, 0.f, 0.f};
            s = __builtin_amdgcn_mfma_f32_16x16x32_bf16(kf0, qf0, s, 0, 0, 0);
            s = __builtin_amdgcn_mfma_f32_16x16x32_bf16(kf1, qf1, s, 0, 0, 0);
            s4[nt] = s;
        }

        // p = 2^s (scale folded into Q; constant offsets cancel in p/Σp)
        #pragma unroll
        for (int nt = 0; nt < 4; nt++)
            #pragma unroll
            for (int r = 0; r < 4; r++) {
                float p = __builtin_amdgcn_exp2f(s4[nt][r]);
                s4[nt][r] = p;
                l_part += p;
            }

        // PV via permuted-k 16x16x32: k=(quad,j) -> kv = (j<4 ? nt0 : nt1)*16 + quad*4 + (j&3)
        // Both operands use the same map => valid dot product.
        #pragma unroll
        for (int h = 0; h < 2; h++) {
            union { u16 s[8]; bf16x8 v; } pk;
            #pragma unroll
            for (int r = 0; r < 4; r++) {
                pk.s[r]     = f2bf(s4[2 * h][r]);
                pk.s[4 + r] = f2bf(s4[2 * h + 1][r]);
            }
            #pragma unroll
            for (int dt = 0; dt < 4; dt++) {
                int drow = dt * 16 + l16;
                int swz = 4 * ((drow >> 3) & 7);
                int c0 = ((2 * h) * 16 + quad * 4) ^ swz;
                int c1 = ((2 * h + 1) * 16 + quad * 4) ^ swz;
                union { u16 s[8]; bf16x8 v; } vk;
                *(uint2*)&vk.s[0] = *(const uint2*)&Vt[drow][c0];
                *(uint2*)&vk.s[4] = *(const uint2*)&Vt[drow][c1];
                Oacc[dt] = __builtin_amdgcn_mfma_f32_16x16x32_bf16(vk.v, pk.v, Oacc[dt], 0, 0, 0);
            }
        }
        __syncthreads();
    }

    // l for column q: reduce across the 4 quads (lanes l16, l16+16, l16+32, l16+48)
    float l = l_part;
    l += __shfl_xor(l, 16);
    l += __shfl_xor(l, 32);
    float rl = __builtin_amdgcn_rcpf(l);

    #pragma unroll
    for (int dt = 0; dt < 4; dt++) {
        union { u16 s[4]; uint2 v; } ok;
        #pragma unroll
        for (int r = 0; r < 4; r++) ok.s[r] = f2bf(Oacc[dt][r] * rl);
        *(uint2*)&QO[qoff + dt * 16 + quad * 4] = ok.v;
    }
}

// -------- out-proj GEMM: A = O bf16 gathered [b,h,n,d], Bt bf16 [768][768] --------
__global__ __launch_bounds__(256) void gemm_out(
    const u16* __restrict__ Qg, const u16* __restrict__ Bt,
    const float* __restrict__ bias, float* __restrict__ out)
{
    const int K = 768;
    __shared__ __align__(16) u16 As[128][40];
    __shared__ __align__(16) u16 Bs[128][40];

    int tid = threadIdx.x;
    int lane = tid & 63, wave = tid >> 6;
    int quad = lane >> 4, l16 = lane & 15;
    int wm = wave >> 1, wn = wave & 1;
    int m0 = blockIdx.y * 128, n0 = blockIdx.x * 128;

    f32x4 acc[4][4];
    #pragma unroll
    for (int i = 0; i < 4; i++)
        #pragma unroll
        for (int j = 0; j < 4; j++) acc[i][j] = (f32x4){0.f, 0.f, 0.f, 0.f};

    for (int kt = 0; kt < K; kt += 32) {
        #pragma unroll
        for (int it = 0; it < 2; ++it) {
            int e = it * 256 + tid;
            int row = e >> 2, c8 = (e & 3) * 8;
            int m = m0 + row, b = m >> 10, npos = m & 1023;
            int k = kt + c8, h = k >> 6, dd = k & 63;
            *(uint4*)&As[row][c8] =
                *(const uint4*)&Qg[(((size_t)(b * 12 + h) * 1024 + npos) << 6) + dd];
            *(uint4*)&Bs[row][c8] = *(const uint4*)&Bt[(size_t)(n0 + row) * K + kt + c8];
        }
        __syncthreads();
        bf16x8 af[4], bfr[4];
        #pragma unroll
        for (int i = 0; i < 4; i++) af[i]  = *(const bf16x8*)&As[wm * 64 + i * 16 + l16][quad * 8];
        #pragma unroll
        for (int j = 0; j < 4; j++) bfr[j] = *(const bf16x8*)&Bs[wn * 64 + j * 16 + l16][quad * 8];
        #pragma unroll
        for (int i = 0; i < 4; i++)
            #pragma unroll
            for (int j = 0; j < 4; j++)
                acc[i][j] = __builtin_amdgcn_mfma_f32_16x16x32_bf16(af[i], bfr[j], acc[i][j], 0, 0, 0);
        __syncthreads();
    }

    #pragma unroll
    for (int i = 0; i < 4; i++) {
        int mbase = m0 + wm * 64 + i * 16 + quad * 4;
        #pragma unroll
        for (int j = 0; j < 4; j++) {
            int n = n0 + wn * 64 + j * 16 + l16;
            float bv = bias[n];
            #pragma unroll
            for (int r = 0; r < 4; r++)
                out[(size_t)(mbase + r) * 768 + n] = acc[i][j][r] + bv;
        }
    }
}

extern "C" void kernel_launch(void* const* d_in, const int* in_sizes, int n_in,
                              void* d_out, int out_size, void* d_ws, size_t ws_size,
                              hipStream_t stream) {
    const float* x     = (const float*)d_in[0];   // [8,1024,768] f32
    const float* w_qkv = (const float*)d_in[1];   // [768,2304] f32
    const float* w_out = (const float*)d_in[2];   // [768,768] f32
    const float* b_out = (const float*)d_in[3];   // [768] f32
    float* out = (float*)d_out;                   // [8,1024,768] f32

    char* ws = (char*)d_ws;
    u16* wtq  = (u16*)(ws);                   // [2304][768] bf16   3,538,944 B
    u16* wto  = (u16*)(ws + 3538944);         // [768][768]  bf16   1,179,648 B
    u16* Qbuf = (u16*)(ws + 4718592);         // [8,12,1024,64] bf16 12,582,912 B
    u16* xbf  = (u16*)(ws + 17301504);        // [8192][768] bf16   12,582,912 B -> 29.9 MB
    // K,V in d_out (2 x 12,582,912 B = exactly out_size*4); consumed before gemm_out writes
    u16* Kbuf = (u16*)d_out;
    u16* Vbuf = (u16*)d_out + 6291456;

    transpose_f32_bf16<<<dim3(72, 24), 256, 0, stream>>>(w_qkv, wtq, 768, 2304);
    transpose_f32_bf16<<<dim3(24, 24), 256, 0, stream>>>(w_out, wto, 768, 768);
    cast_f32_bf16<<<dim3(3072), 256, 0, stream>>>(x, xbf);
    gemm_qkv<<<dim3(18, 64), 256, 0, stream>>>(xbf, wtq, Qbuf, Kbuf, Vbuf);
    attn64<<<dim3(16, 96), 256, 0, stream>>>(Qbuf, Kbuf, Vbuf);
    gemm_out<<<dim3(6, 64), 256, 0, stream>>>(Qbuf, wto, b_out, out);
}

// Round 4
// 210.910 us; speedup vs baseline: 1.4293x; 1.0795x over previous
//
#include <hip/hip_runtime.h>

typedef unsigned short u16;
typedef __bf16 bf16x8 __attribute__((ext_vector_type(8)));
typedef float f32x4 __attribute__((ext_vector_type(4)));

__device__ inline u16 f2bf(float f) {
    union { float f; unsigned int u; } a; a.f = f;
    unsigned int u = a.u + 0x7fffu + ((a.u >> 16) & 1u);
    return (u16)(u >> 16);
}

// async global->LDS, 16B per lane. LDS side is wave-uniform base + lane*16.
__device__ __forceinline__ void cp16(const void* g, void* l) {
    __builtin_amdgcn_global_load_lds(
        (const __attribute__((address_space(1))) unsigned int*)g,
        (__attribute__((address_space(3))) unsigned int*)l, 16, 0, 0);
}

// -------- prep: fuse x-cast + both weight transposes (1 launch) --------
__global__ __launch_bounds__(256) void prep(
    const float* __restrict__ x, const float* __restrict__ wq,
    const float* __restrict__ wo, u16* __restrict__ xbf,
    u16* __restrict__ wtq, u16* __restrict__ wto)
{
    int bid = blockIdx.x;
    if (bid < 3072) {                      // cast x: f32 -> bf16, 8/thread
        size_t base = ((size_t)bid * 256 + threadIdx.x) * 8;
        float4 f0 = *(const float4*)&x[base];
        float4 f1 = *(const float4*)&x[base + 4];
        union { u16 s[8]; uint4 v; } t;
        t.s[0]=f2bf(f0.x); t.s[1]=f2bf(f0.y); t.s[2]=f2bf(f0.z); t.s[3]=f2bf(f0.w);
        t.s[4]=f2bf(f1.x); t.s[5]=f2bf(f1.y); t.s[6]=f2bf(f1.z); t.s[7]=f2bf(f1.w);
        *(uint4*)&xbf[base] = t.v;
        return;
    }
    __shared__ u16 tile[32][33];
    const float* in; u16* outp; int N, bx, by;
    if (bid < 3072 + 1728) { int t = bid - 3072; in = wq; outp = wtq; N = 2304; bx = t % 72; by = t / 72; }
    else                   { int t = bid - 4800; in = wo; outp = wto; N = 768;  bx = t % 24; by = t / 24; }
    int n0 = bx * 32, k0 = by * 32;
    int tx = threadIdx.x & 31, ty = threadIdx.x >> 5;
    #pragma unroll
    for (int r = ty; r < 32; r += 8)
        tile[r][tx] = f2bf(in[(size_t)(k0 + r) * N + n0 + tx]);
    __syncthreads();
    #pragma unroll
    for (int r = ty; r < 32; r += 8)
        outp[(size_t)(n0 + r) * 768 + k0 + tx] = tile[tx][r];
}

// -------- QKV GEMM (m97-style async staging): A bf16 [8192][768], Bt [2304][768] --------
// Q (*0.125*log2e) -> [b,h,n,64]; K -> [b,h,n,64]; V -> TRANSPOSED [b,h,d,n]
__global__ __launch_bounds__(256) void gemm_qkv(
    const u16* __restrict__ A, const u16* __restrict__ Bt,
    u16* __restrict__ q_out, u16* __restrict__ k_out, u16* __restrict__ v_out)
{
    const int K = 768;
    __shared__ __align__(16) u16 As[128 * 32];   // unpadded, lane-ordered
    __shared__ __align__(16) u16 Bs[128 * 32];

    int tid = threadIdx.x;
    int lane = tid & 63, wave = tid >> 6;
    int quad = lane >> 4, l16 = lane & 15;
    int wm = wave >> 1, wn = wave & 1;
    int m0 = blockIdx.y * 128, n0 = blockIdx.x * 128;

    f32x4 acc[4][4];
    #pragma unroll
    for (int i = 0; i < 4; i++)
        #pragma unroll
        for (int j = 0; j < 4; j++) acc[i][j] = (f32x4){0.f, 0.f, 0.f, 0.f};

    int r0 = tid >> 2, c0 = (tid & 3) * 8;
    for (int kt = 0; kt < K; kt += 32) {
        cp16(&A [(size_t)(m0 + r0)      * K + kt + c0], &As[(size_t)tid * 8]);
        cp16(&A [(size_t)(m0 + 64 + r0) * K + kt + c0], &As[(size_t)(256 + tid) * 8]);
        cp16(&Bt[(size_t)(n0 + r0)      * K + kt + c0], &Bs[(size_t)tid * 8]);
        cp16(&Bt[(size_t)(n0 + 64 + r0) * K + kt + c0], &Bs[(size_t)(256 + tid) * 8]);
        __syncthreads();
        bf16x8 af[4], bfr[4];
        #pragma unroll
        for (int i = 0; i < 4; i++) af[i]  = *(const bf16x8*)&As[(wm * 64 + i * 16 + l16) * 32 + quad * 8];
        #pragma unroll
        for (int j = 0; j < 4; j++) bfr[j] = *(const bf16x8*)&Bs[(wn * 64 + j * 16 + l16) * 32 + quad * 8];
        #pragma unroll
        for (int i = 0; i < 4; i++)
            #pragma unroll
            for (int j = 0; j < 4; j++)
                acc[i][j] = __builtin_amdgcn_mfma_f32_16x16x32_bf16(af[i], bfr[j], acc[i][j], 0, 0, 0);
        __syncthreads();
    }

    // C/D layout: col = l16, row = quad*4 + r
    #pragma unroll
    for (int i = 0; i < 4; i++) {
        int mbase = m0 + wm * 64 + i * 16 + quad * 4;
        int b = mbase >> 10, npos = mbase & 1023;
        #pragma unroll
        for (int j = 0; j < 4; j++) {
            int n = n0 + wn * 64 + j * 16 + l16;
            int part  = n >= 1536 ? 2 : (n >= 768 ? 1 : 0);
            int inner = n - part * 768;
            int h = inner >> 6, dd = inner & 63;
            if (part == 2) {   // V^T: [b,h,d,n] — 4 consecutive npos -> one 8B store
                union { u16 s[4]; uint2 v; } pk;
                #pragma unroll
                for (int r = 0; r < 4; r++) pk.s[r] = f2bf(acc[i][j][r]);
                *(uint2*)&v_out[((size_t)((b * 12 + h) * 64 + dd)) * 1024 + npos] = pk.v;
            } else {
                #pragma unroll
                for (int r = 0; r < 4; r++) {
                    size_t idx = ((size_t)((b * 12 + h) * 1024 + npos + r)) * 64 + dd;
                    float v = acc[i][j][r];
                    if (part == 0) q_out[idx] = f2bf(v * 0.18033688011112042f); // /8 * log2e
                    else           k_out[idx] = f2bf(v);
                }
            }
        }
    }
}

// -------- attention: S^T form, 128 q/block, all staging async+swizzled --------
__global__ __launch_bounds__(256) void attn128(
    u16* __restrict__ QO, const u16* __restrict__ Kg, const u16* __restrict__ Vtg)
{
    __shared__ __align__(16) u16 Ks[64 * 64];   // [kv][d], 8-elem groups XOR-swizzled
    __shared__ __align__(16) u16 Vs[64 * 64];   // [d][kv], 8-elem groups XOR-swizzled

    int tid = threadIdx.x;
    int lane = tid & 63, wave = tid >> 6;
    int quad = lane >> 4, l16 = lane & 15;
    int bh = blockIdx.y;
    int q0 = blockIdx.x * 128;
    const size_t head_base = (size_t)bh * 65536;

    // Q as B-operand: n = q, k = d = quad*8+j; pre-scaled by 0.125*log2e
    size_t qoff[2];
    bf16x8 qf[2][2];
    #pragma unroll
    for (int qs = 0; qs < 2; qs++) {
        qoff[qs] = head_base + (size_t)(q0 + wave * 32 + qs * 16 + l16) * 64;
        qf[qs][0] = *(const bf16x8*)&QO[qoff[qs] + quad * 8];
        qf[qs][1] = *(const bf16x8*)&QO[qoff[qs] + 32 + quad * 8];
    }

    f32x4 Oacc[4][2];   // O^T: d = dt*16 + quad*4 + r, q col = l16
    #pragma unroll
    for (int dt = 0; dt < 4; dt++)
        #pragma unroll
        for (int qs = 0; qs < 2; qs++) Oacc[dt][qs] = (f32x4){0.f, 0.f, 0.f, 0.f};
    float l_part[2] = {0.f, 0.f};

    int srow = tid >> 3, sg = tid & 7;                    // staging coords (it=0)
    for (int j0 = 0; j0 < 1024; j0 += 64) {
        #pragma unroll
        for (int it = 0; it < 2; ++it) {
            int e = it * 256 + tid, row = it * 32 + srow, gs = sg ^ (row & 7);
            cp16(&Kg [head_base + (size_t)(j0 + row) * 64 + gs * 8], &Ks[(size_t)e * 8]);
            cp16(&Vtg[head_base + (size_t)row * 1024 + j0 + gs * 8], &Vs[(size_t)e * 8]);
        }
        __syncthreads();

        // S^T = K Q^T : D[kv][q]
        f32x4 s4[4][2];
        #pragma unroll
        for (int nt = 0; nt < 4; nt++) {
            int R = nt * 16 + l16;
            bf16x8 kf0 = *(const bf16x8*)&Ks[R * 64 + ((quad       ^ (R & 7)) * 8)];
            bf16x8 kf1 = *(const bf16x8*)&Ks[R * 64 + (((quad + 4) ^ (R & 7)) * 8)];
            #pragma unroll
            for (int qs = 0; qs < 2; qs++) {
                f32x4 s = (f32x4){0.f, 0.f, 0.f, 0.f};
                s = __builtin_amdgcn_mfma_f32_16x16x32_bf16(kf0, qf[qs][0], s, 0, 0, 0);
                s = __builtin_amdgcn_mfma_f32_16x16x32_bf16(kf1, qf[qs][1], s, 0, 0, 0);
                s4[nt][qs] = s;
            }
        }

        // p = 2^s (constant offsets cancel in p/Σp)
        #pragma unroll
        for (int nt = 0; nt < 4; nt++)
            #pragma unroll
            for (int qs = 0; qs < 2; qs++)
                #pragma unroll
                for (int r = 0; r < 4; r++) {
                    float p = __builtin_amdgcn_exp2f(s4[nt][qs][r]);
                    s4[nt][qs][r] = p;
                    l_part[qs] += p;
                }

        // PV, permuted-k: k=(quad,j) -> kv = (j<4 ? 2h : 2h+1)*16 + quad*4 + (j&3)
        #pragma unroll
        for (int h = 0; h < 2; h++) {
            union { u16 s[8]; bf16x8 v; } pk[2];
            #pragma unroll
            for (int qs = 0; qs < 2; qs++)
                #pragma unroll
                for (int r = 0; r < 4; r++) {
                    pk[qs].s[r]     = f2bf(s4[2 * h][qs][r]);
                    pk[qs].s[4 + r] = f2bf(s4[2 * h + 1][qs][r]);
                }
            int lg0 = 4 * h + (quad >> 1), lg1 = lg0 + 2;   // kv-groups of the two 8B halves
            int off = (quad & 1) * 4;
            #pragma unroll
            for (int dt = 0; dt < 4; dt++) {
                int drow = dt * 16 + l16;
                union { u16 s[8]; bf16x8 v; } vk;
                *(uint2*)&vk.s[0] = *(const uint2*)&Vs[drow * 64 + (lg0 ^ (drow & 7)) * 8 + off];
                *(uint2*)&vk.s[4] = *(const uint2*)&Vs[drow * 64 + (lg1 ^ (drow & 7)) * 8 + off];
                #pragma unroll
                for (int qs = 0; qs < 2; qs++)
                    Oacc[dt][qs] = __builtin_amdgcn_mfma_f32_16x16x32_bf16(vk.v, pk[qs].v, Oacc[dt][qs], 0, 0, 0);
            }
        }
        __syncthreads();
    }

    #pragma unroll
    for (int qs = 0; qs < 2; qs++) {
        float l = l_part[qs];
        l += __shfl_xor(l, 16);
        l += __shfl_xor(l, 32);
        float rl = __builtin_amdgcn_rcpf(l);
        #pragma unroll
        for (int dt = 0; dt < 4; dt++) {
            union { u16 s[4]; uint2 v; } ok;
            #pragma unroll
            for (int r = 0; r < 4; r++) ok.s[r] = f2bf(Oacc[dt][qs][r] * rl);
            *(uint2*)&QO[qoff[qs] + dt * 16 + quad * 4] = ok.v;
        }
    }
}

// -------- out-proj GEMM: A = O bf16 gathered [b,h,n,d], Bt [768][768], out fp32+bias --------
__global__ __launch_bounds__(256) void gemm_out(
    const u16* __restrict__ Qg, const u16* __restrict__ Bt,
    const float* __restrict__ bias, float* __restrict__ out)
{
    const int K = 768;
    __shared__ __align__(16) u16 As[128 * 32];
    __shared__ __align__(16) u16 Bs[128 * 32];

    int tid = threadIdx.x;
    int lane = tid & 63, wave = tid >> 6;
    int quad = lane >> 4, l16 = lane & 15;
    int wm = wave >> 1, wn = wave & 1;
    int m0 = blockIdx.y * 128, n0 = blockIdx.x * 128;

    f32x4 acc[4][4];
    #pragma unroll
    for (int i = 0; i < 4; i++)
        #pragma unroll
        for (int j = 0; j < 4; j++) acc[i][j] = (f32x4){0.f, 0.f, 0.f, 0.f};

    int r0 = tid >> 2, c0 = (tid & 3) * 8;
    for (int kt = 0; kt < K; kt += 32) {
        int k = kt + c0, h = k >> 6, dd = k & 63;
        #pragma unroll
        for (int it = 0; it < 2; ++it) {
            int m = m0 + it * 64 + r0, b = m >> 10, npos = m & 1023;
            cp16(&Qg[(((size_t)(b * 12 + h) * 1024 + npos) << 6) + dd],
                 &As[(size_t)(it * 256 + tid) * 8]);
            cp16(&Bt[(size_t)(n0 + it * 64 + r0) * K + kt + c0],
                 &Bs[(size_t)(it * 256 + tid) * 8]);
        }
        __syncthreads();
        bf16x8 af[4], bfr[4];
        #pragma unroll
        for (int i = 0; i < 4; i++) af[i]  = *(const bf16x8*)&As[(wm * 64 + i * 16 + l16) * 32 + quad * 8];
        #pragma unroll
        for (int j = 0; j < 4; j++) bfr[j] = *(const bf16x8*)&Bs[(wn * 64 + j * 16 + l16) * 32 + quad * 8];
        #pragma unroll
        for (int i = 0; i < 4; i++)
            #pragma unroll
            for (int j = 0; j < 4; j++)
                acc[i][j] = __builtin_amdgcn_mfma_f32_16x16x32_bf16(af[i], bfr[j], acc[i][j], 0, 0, 0);
        __syncthreads();
    }

    #pragma unroll
    for (int i = 0; i < 4; i++) {
        int mbase = m0 + wm * 64 + i * 16 + quad * 4;
        #pragma unroll
        for (int j = 0; j < 4; j++) {
            int n = n0 + wn * 64 + j * 16 + l16;
            float bv = bias[n];
            #pragma unroll
            for (int r = 0; r < 4; r++)
                out[(size_t)(mbase + r) * 768 + n] = acc[i][j][r] + bv;
        }
    }
}

extern "C" void kernel_launch(void* const* d_in, const int* in_sizes, int n_in,
                              void* d_out, int out_size, void* d_ws, size_t ws_size,
                              hipStream_t stream) {
    const float* x     = (const float*)d_in[0];   // [8,1024,768] f32
    const float* w_qkv = (const float*)d_in[1];   // [768,2304] f32
    const float* w_out = (const float*)d_in[2];   // [768,768] f32
    const float* b_out = (const float*)d_in[3];   // [768] f32
    float* out = (float*)d_out;                   // [8,1024,768] f32

    char* ws = (char*)d_ws;
    u16* wtq  = (u16*)(ws);                   // [2304][768] bf16    3,538,944 B
    u16* wto  = (u16*)(ws + 3538944);         // [768][768]  bf16    1,179,648 B
    u16* Qbuf = (u16*)(ws + 4718592);         // [8,12,1024,64] bf16 12,582,912 B
    u16* xbf  = (u16*)(ws + 17301504);        // [8192][768] bf16    12,582,912 B  (29.9 MB)
    // K natural [b,h,n,64] and V TRANSPOSED [b,h,64,n] live in d_out (2x12.58 MB);
    // both fully consumed by attn128 before gemm_out overwrites d_out.
    u16* Kbuf = (u16*)d_out;
    u16* Vbuf = (u16*)d_out + 6291456;

    prep<<<dim3(5376), 256, 0, stream>>>(x, w_qkv, w_out, xbf, wtq, wto);
    gemm_qkv<<<dim3(18, 64), 256, 0, stream>>>(xbf, wtq, Qbuf, Kbuf, Vbuf);
    attn128<<<dim3(8, 96), 256, 0, stream>>>(Qbuf, Kbuf, Vbuf);
    gemm_out<<<dim3(6, 64), 256, 0, stream>>>(Qbuf, wto, b_out, out);
}

// Round 5
// 201.242 us; speedup vs baseline: 1.4980x; 1.0480x over previous
//
#include <hip/hip_runtime.h>

typedef unsigned short u16;
typedef __bf16 bf16x8 __attribute__((ext_vector_type(8)));
typedef float f32x4 __attribute__((ext_vector_type(4)));

__device__ inline u16 f2bf(float f) {
    union { float f; unsigned int u; } a; a.f = f;
    unsigned int u = a.u + 0x7fffu + ((a.u >> 16) & 1u);
    return (u16)(u >> 16);
}

// async global->LDS, 16B per lane. LDS side is wave-uniform base + lane*16.
__device__ __forceinline__ void cp16(const void* g, void* l) {
    __builtin_amdgcn_global_load_lds(
        (const __attribute__((address_space(1))) unsigned int*)g,
        (__attribute__((address_space(3))) unsigned int*)l, 16, 0, 0);
}

// -------- prep: fuse x-cast + both weight transposes (1 launch) --------
__global__ __launch_bounds__(256) void prep(
    const float* __restrict__ x, const float* __restrict__ wq,
    const float* __restrict__ wo, u16* __restrict__ xbf,
    u16* __restrict__ wtq, u16* __restrict__ wto)
{
    int bid = blockIdx.x;
    if (bid < 3072) {                      // cast x: f32 -> bf16, 8/thread
        size_t base = ((size_t)bid * 256 + threadIdx.x) * 8;
        float4 f0 = *(const float4*)&x[base];
        float4 f1 = *(const float4*)&x[base + 4];
        union { u16 s[8]; uint4 v; } t;
        t.s[0]=f2bf(f0.x); t.s[1]=f2bf(f0.y); t.s[2]=f2bf(f0.z); t.s[3]=f2bf(f0.w);
        t.s[4]=f2bf(f1.x); t.s[5]=f2bf(f1.y); t.s[6]=f2bf(f1.z); t.s[7]=f2bf(f1.w);
        *(uint4*)&xbf[base] = t.v;
        return;
    }
    __shared__ u16 tile[32][33];
    const float* in; u16* outp; int N, bx, by;
    if (bid < 3072 + 1728) { int t = bid - 3072; in = wq; outp = wtq; N = 2304; bx = t % 72; by = t / 72; }
    else                   { int t = bid - 4800; in = wo; outp = wto; N = 768;  bx = t % 24; by = t / 24; }
    int n0 = bx * 32, k0 = by * 32;
    int tx = threadIdx.x & 31, ty = threadIdx.x >> 5;
    #pragma unroll
    for (int r = ty; r < 32; r += 8)
        tile[r][tx] = f2bf(in[(size_t)(k0 + r) * N + n0 + tx]);
    __syncthreads();
    #pragma unroll
    for (int r = ty; r < 32; r += 8)
        outp[(size_t)(n0 + r) * 768 + k0 + tx] = tile[tx][r];
}

// -------- QKV GEMM, BK=64, swizzled staging, full-line LDS epilogue --------
// A bf16 [8192][768], Bt bf16 [2304][768]
// Q (*0.125*log2e) -> [b,h,n,64]; K -> [b,h,n,64]; V -> TRANSPOSED [b,h,d,n]
__global__ __launch_bounds__(256) void gemm_qkv(
    const u16* __restrict__ A, const u16* __restrict__ Bt,
    u16* __restrict__ q_out, u16* __restrict__ k_out, u16* __restrict__ v_out)
{
    const int K = 768;
    __shared__ __align__(16) u16 As[128 * 64];   // 16 KB; slot s of row R holds k-group s^(R&7)
    __shared__ __align__(16) u16 Bs[128 * 64];   // 16 KB

    int tid = threadIdx.x;
    int lane = tid & 63, wave = tid >> 6;
    int quad = lane >> 4, l16 = lane & 15;
    int wm = wave >> 1, wn = wave & 1;
    int m0 = blockIdx.y * 128, n0 = blockIdx.x * 128;

    f32x4 acc[4][4];
    #pragma unroll
    for (int i = 0; i < 4; i++)
        #pragma unroll
        for (int j = 0; j < 4; j++) acc[i][j] = (f32x4){0.f, 0.f, 0.f, 0.f};

    int r0 = tid >> 3, cg = tid & 7;
    for (int kt = 0; kt < K; kt += 64) {
        #pragma unroll
        for (int it = 0; it < 4; ++it) {
            int row = it * 32 + r0;
            int g = cg ^ (row & 7);
            cp16(&A [(size_t)(m0 + row) * K + kt + g * 8], &As[(size_t)(it * 256 + tid) * 8]);
            cp16(&Bt[(size_t)(n0 + row) * K + kt + g * 8], &Bs[(size_t)(it * 256 + tid) * 8]);
        }
        __syncthreads();
        #pragma unroll
        for (int ko = 0; ko < 2; ko++) {
            bf16x8 af[4], bfr[4];
            #pragma unroll
            for (int i = 0; i < 4; i++) {
                int R = wm * 64 + i * 16 + l16;
                af[i] = *(const bf16x8*)&As[R * 64 + (((ko * 4 + quad) ^ (R & 7)) * 8)];
            }
            #pragma unroll
            for (int j = 0; j < 4; j++) {
                int R = wn * 64 + j * 16 + l16;
                bfr[j] = *(const bf16x8*)&Bs[R * 64 + (((ko * 4 + quad) ^ (R & 7)) * 8)];
            }
            #pragma unroll
            for (int i = 0; i < 4; i++)
                #pragma unroll
                for (int j = 0; j < 4; j++)
                    acc[i][j] = __builtin_amdgcn_mfma_f32_16x16x32_bf16(af[i], bfr[j], acc[i][j], 0, 0, 0);
        }
        __syncthreads();
    }

    // ---- epilogue: wave tile = 64 m x 64 n, one (part,h); round-trip via LDS ----
    int M0 = m0 + wm * 64, N0 = n0 + wn * 64;
    int part = N0 >= 1536 ? 2 : (N0 >= 768 ? 1 : 0);
    int h = (N0 - part * 768) >> 6;
    int b = M0 >> 10, npos0 = M0 & 1023;
    u16* ep = (wave < 2 ? As : Bs) + (wave & 1) * 4096;   // 8 KB per wave

    if (part != 2) {
        float scale = (part == 0) ? 0.18033688011112042f : 1.0f;   // /8 * log2e for Q
        u16* gbase = (part == 0 ? q_out : k_out) + (((size_t)(b * 12 + h) * 1024 + npos0) << 6);
        // write [np][dd], group-swizzled by np
        #pragma unroll
        for (int i = 0; i < 4; i++)
            #pragma unroll
            for (int j = 0; j < 4; j++) {
                int dd = j * 16 + l16;
                #pragma unroll
                for (int r = 0; r < 4; r++) {
                    int np = i * 16 + quad * 4 + r;
                    ep[np * 64 + (((dd >> 3) ^ (np & 7)) * 8) + (dd & 7)] =
                        f2bf(acc[i][j][r] * scale);
                }
            }
        __syncthreads();
        // read rows, store 8 KB contiguous as dwordx4 (full 128B lines)
        #pragma unroll
        for (int t = 0; t < 8; t++) {
            int idx = t * 512 + lane * 8;           // u16 units
            int np = idx >> 6;
            int slot = ((lane & 7) ^ (np & 7));
            uint4 v = *(const uint4*)&ep[np * 64 + slot * 8];
            *(uint4*)&gbase[idx] = v;
        }
    } else {
        // V^T: LDS [dd][np], group-swizzled by dd; b64 packed writes (r-consecutive np)
        #pragma unroll
        for (int i = 0; i < 4; i++)
            #pragma unroll
            for (int j = 0; j < 4; j++) {
                int dd = j * 16 + l16;
                int npg = i * 2 + (quad >> 1);
                int sub = (quad & 1) * 4;
                union { u16 s[4]; uint2 v; } pk;
                #pragma unroll
                for (int r = 0; r < 4; r++) pk.s[r] = f2bf(acc[i][j][r]);
                *(uint2*)&ep[dd * 64 + ((npg ^ (dd & 7)) * 8) + sub] = pk.v;
            }
        __syncthreads();
        // read dd-rows, store 128B per dd (full sectors), np-contiguous in global
        #pragma unroll
        for (int t = 0; t < 8; t++) {
            int dd = t * 8 + (lane >> 3);
            int npg = lane & 7;
            uint4 v = *(const uint4*)&ep[dd * 64 + ((npg ^ (dd & 7)) * 8)];
            *(uint4*)&v_out[((size_t)((b * 12 + h) * 64 + dd)) * 1024 + npos0 + npg * 8] = v;
        }
    }
}

// -------- attention: S^T form, 128 q/block, async+swizzled staging --------
__global__ __launch_bounds__(256) void attn128(
    u16* __restrict__ QO, const u16* __restrict__ Kg, const u16* __restrict__ Vtg)
{
    __shared__ __align__(16) u16 Ks[64 * 64];   // [kv][d], 8-elem groups XOR-swizzled
    __shared__ __align__(16) u16 Vs[64 * 64];   // [d][kv], 8-elem groups XOR-swizzled

    int tid = threadIdx.x;
    int lane = tid & 63, wave = tid >> 6;
    int quad = lane >> 4, l16 = lane & 15;
    int bh = blockIdx.y;
    int q0 = blockIdx.x * 128;
    const size_t head_base = (size_t)bh * 65536;

    size_t qoff[2];
    bf16x8 qf[2][2];
    #pragma unroll
    for (int qs = 0; qs < 2; qs++) {
        qoff[qs] = head_base + (size_t)(q0 + wave * 32 + qs * 16 + l16) * 64;
        qf[qs][0] = *(const bf16x8*)&QO[qoff[qs] + quad * 8];
        qf[qs][1] = *(const bf16x8*)&QO[qoff[qs] + 32 + quad * 8];
    }

    f32x4 Oacc[4][2];
    #pragma unroll
    for (int dt = 0; dt < 4; dt++)
        #pragma unroll
        for (int qs = 0; qs < 2; qs++) Oacc[dt][qs] = (f32x4){0.f, 0.f, 0.f, 0.f};
    float l_part[2] = {0.f, 0.f};

    int srow = tid >> 3, sg = tid & 7;
    for (int j0 = 0; j0 < 1024; j0 += 64) {
        #pragma unroll
        for (int it = 0; it < 2; ++it) {
            int e = it * 256 + tid, row = it * 32 + srow, gs = sg ^ (row & 7);
            cp16(&Kg [head_base + (size_t)(j0 + row) * 64 + gs * 8], &Ks[(size_t)e * 8]);
            cp16(&Vtg[head_base + (size_t)row * 1024 + j0 + gs * 8], &Vs[(size_t)e * 8]);
        }
        __syncthreads();

        f32x4 s4[4][2];
        #pragma unroll
        for (int nt = 0; nt < 4; nt++) {
            int R = nt * 16 + l16;
            bf16x8 kf0 = *(const bf16x8*)&Ks[R * 64 + ((quad       ^ (R & 7)) * 8)];
            bf16x8 kf1 = *(const bf16x8*)&Ks[R * 64 + (((quad + 4) ^ (R & 7)) * 8)];
            #pragma unroll
            for (int qs = 0; qs < 2; qs++) {
                f32x4 s = (f32x4){0.f, 0.f, 0.f, 0.f};
                s = __builtin_amdgcn_mfma_f32_16x16x32_bf16(kf0, qf[qs][0], s, 0, 0, 0);
                s = __builtin_amdgcn_mfma_f32_16x16x32_bf16(kf1, qf[qs][1], s, 0, 0, 0);
                s4[nt][qs] = s;
            }
        }

        #pragma unroll
        for (int nt = 0; nt < 4; nt++)
            #pragma unroll
            for (int qs = 0; qs < 2; qs++)
                #pragma unroll
                for (int r = 0; r < 4; r++) {
                    float p = __builtin_amdgcn_exp2f(s4[nt][qs][r]);
                    s4[nt][qs][r] = p;
                    l_part[qs] += p;
                }

        #pragma unroll
        for (int h = 0; h < 2; h++) {
            union { u16 s[8]; bf16x8 v; } pk[2];
            #pragma unroll
            for (int qs = 0; qs < 2; qs++)
                #pragma unroll
                for (int r = 0; r < 4; r++) {
                    pk[qs].s[r]     = f2bf(s4[2 * h][qs][r]);
                    pk[qs].s[4 + r] = f2bf(s4[2 * h + 1][qs][r]);
                }
            int lg0 = 4 * h + (quad >> 1), lg1 = lg0 + 2;
            int off = (quad & 1) * 4;
            #pragma unroll
            for (int dt = 0; dt < 4; dt++) {
                int drow = dt * 16 + l16;
                union { u16 s[8]; bf16x8 v; } vk;
                *(uint2*)&vk.s[0] = *(const uint2*)&Vs[drow * 64 + (lg0 ^ (drow & 7)) * 8 + off];
                *(uint2*)&vk.s[4] = *(const uint2*)&Vs[drow * 64 + (lg1 ^ (drow & 7)) * 8 + off];
                #pragma unroll
                for (int qs = 0; qs < 2; qs++)
                    Oacc[dt][qs] = __builtin_amdgcn_mfma_f32_16x16x32_bf16(vk.v, pk[qs].v, Oacc[dt][qs], 0, 0, 0);
            }
        }
        __syncthreads();
    }

    #pragma unroll
    for (int qs = 0; qs < 2; qs++) {
        float l = l_part[qs];
        l += __shfl_xor(l, 16);
        l += __shfl_xor(l, 32);
        float rl = __builtin_amdgcn_rcpf(l);
        #pragma unroll
        for (int dt = 0; dt < 4; dt++) {
            union { u16 s[4]; uint2 v; } ok;
            #pragma unroll
            for (int r = 0; r < 4; r++) ok.s[r] = f2bf(Oacc[dt][qs][r] * rl);
            *(uint2*)&QO[qoff[qs] + dt * 16 + quad * 4] = ok.v;
        }
    }
}

// -------- out-proj GEMM, BK=64: A = O bf16 gathered [b,h,n,d], Bt [768][768] --------
__global__ __launch_bounds__(256) void gemm_out(
    const u16* __restrict__ Qg, const u16* __restrict__ Bt,
    const float* __restrict__ bias, float* __restrict__ out)
{
    const int K = 768;
    __shared__ __align__(16) u16 As[128 * 64];
    __shared__ __align__(16) u16 Bs[128 * 64];

    int tid = threadIdx.x;
    int lane = tid & 63, wave = tid >> 6;
    int quad = lane >> 4, l16 = lane & 15;
    int wm = wave >> 1, wn = wave & 1;
    int m0 = blockIdx.y * 128, n0 = blockIdx.x * 128;

    f32x4 acc[4][4];
    #pragma unroll
    for (int i = 0; i < 4; i++)
        #pragma unroll
        for (int j = 0; j < 4; j++) acc[i][j] = (f32x4){0.f, 0.f, 0.f, 0.f};

    int r0 = tid >> 3, cg = tid & 7;
    for (int kt = 0; kt < K; kt += 64) {
        int h = kt >> 6;
        #pragma unroll
        for (int it = 0; it < 4; ++it) {
            int row = it * 32 + r0;
            int g = cg ^ (row & 7);
            int m = m0 + row, b = m >> 10, npos = m & 1023;
            cp16(&Qg[(((size_t)(b * 12 + h) * 1024 + npos) << 6) + g * 8],
                 &As[(size_t)(it * 256 + tid) * 8]);
            cp16(&Bt[(size_t)(n0 + row) * K + kt + g * 8],
                 &Bs[(size_t)(it * 256 + tid) * 8]);
        }
        __syncthreads();
        #pragma unroll
        for (int ko = 0; ko < 2; ko++) {
            bf16x8 af[4], bfr[4];
            #pragma unroll
            for (int i = 0; i < 4; i++) {
                int R = wm * 64 + i * 16 + l16;
                af[i] = *(const bf16x8*)&As[R * 64 + (((ko * 4 + quad) ^ (R & 7)) * 8)];
            }
            #pragma unroll
            for (int j = 0; j < 4; j++) {
                int R = wn * 64 + j * 16 + l16;
                bfr[j] = *(const bf16x8*)&Bs[R * 64 + (((ko * 4 + quad) ^ (R & 7)) * 8)];
            }
            #pragma unroll
            for (int i = 0; i < 4; i++)
                #pragma unroll
                for (int j = 0; j < 4; j++)
                    acc[i][j] = __builtin_amdgcn_mfma_f32_16x16x32_bf16(af[i], bfr[j], acc[i][j], 0, 0, 0);
        }
        __syncthreads();
    }

    #pragma unroll
    for (int i = 0; i < 4; i++) {
        int mbase = m0 + wm * 64 + i * 16 + quad * 4;
        #pragma unroll
        for (int j = 0; j < 4; j++) {
            int n = n0 + wn * 64 + j * 16 + l16;
            float bv = bias[n];
            #pragma unroll
            for (int r = 0; r < 4; r++)
                out[(size_t)(mbase + r) * 768 + n] = acc[i][j][r] + bv;
        }
    }
}

extern "C" void kernel_launch(void* const* d_in, const int* in_sizes, int n_in,
                              void* d_out, int out_size, void* d_ws, size_t ws_size,
                              hipStream_t stream) {
    const float* x     = (const float*)d_in[0];   // [8,1024,768] f32
    const float* w_qkv = (const float*)d_in[1];   // [768,2304] f32
    const float* w_out = (const float*)d_in[2];   // [768,768] f32
    const float* b_out = (const float*)d_in[3];   // [768] f32
    float* out = (float*)d_out;                   // [8,1024,768] f32

    char* ws = (char*)d_ws;
    u16* wtq  = (u16*)(ws);                   // [2304][768] bf16    3,538,944 B
    u16* wto  = (u16*)(ws + 3538944);         // [768][768]  bf16    1,179,648 B
    u16* Qbuf = (u16*)(ws + 4718592);         // [8,12,1024,64] bf16 12,582,912 B
    u16* xbf  = (u16*)(ws + 17301504);        // [8192][768] bf16    12,582,912 B  (29.9 MB)
    // K natural [b,h,n,64] and V TRANSPOSED [b,h,64,n] live in d_out (2x12.58 MB);
    // both fully consumed by attn128 before gemm_out overwrites d_out.
    u16* Kbuf = (u16*)d_out;
    u16* Vbuf = (u16*)d_out + 6291456;

    prep<<<dim3(5376), 256, 0, stream>>>(x, w_qkv, w_out, xbf, wtq, wto);
    gemm_qkv<<<dim3(18, 64), 256, 0, stream>>>(xbf, wtq, Qbuf, Kbuf, Vbuf);
    attn128<<<dim3(8, 96), 256, 0, stream>>>(Qbuf, Kbuf, Vbuf);
    gemm_out<<<dim3(6, 64), 256, 0, stream>>>(Qbuf, wto, b_out, out);
}

// Round 6
// 194.342 us; speedup vs baseline: 1.5512x; 1.0355x over previous
//
#include <hip/hip_runtime.h>

typedef unsigned short u16;
typedef __bf16 bf16x8 __attribute__((ext_vector_type(8)));
typedef float f32x4 __attribute__((ext_vector_type(4)));

__device__ inline u16 f2bf(float f) {
    union { float f; unsigned int u; } a; a.f = f;
    unsigned int u = a.u + 0x7fffu + ((a.u >> 16) & 1u);
    return (u16)(u >> 16);
}
// truncate f32 -> bf16; returns truncated value as f32 and the bf16 bits
__device__ __forceinline__ float truncbf(float f, u16& h) {
    union { float f; unsigned int u; } a; a.f = f;
    a.u &= 0xffff0000u;
    h = (u16)(a.u >> 16);
    return a.f;
}

// async global->LDS, 16B per lane. LDS side is wave-uniform base + lane*16.
__device__ __forceinline__ void cp16(const void* g, void* l) {
    __builtin_amdgcn_global_load_lds(
        (const __attribute__((address_space(1))) unsigned int*)g,
        (__attribute__((address_space(3))) unsigned int*)l, 16, 0, 0);
}

// -------- prep: fuse x-cast + both weight transposes (1 launch) --------
__global__ __launch_bounds__(256) void prep(
    const float* __restrict__ x, const float* __restrict__ wq,
    const float* __restrict__ wo, u16* __restrict__ xbf,
    u16* __restrict__ wtq, u16* __restrict__ wto)
{
    int bid = blockIdx.x;
    if (bid < 3072) {                      // cast x: f32 -> bf16, 8/thread
        size_t base = ((size_t)bid * 256 + threadIdx.x) * 8;
        float4 f0 = *(const float4*)&x[base];
        float4 f1 = *(const float4*)&x[base + 4];
        union { u16 s[8]; uint4 v; } t;
        t.s[0]=f2bf(f0.x); t.s[1]=f2bf(f0.y); t.s[2]=f2bf(f0.z); t.s[3]=f2bf(f0.w);
        t.s[4]=f2bf(f1.x); t.s[5]=f2bf(f1.y); t.s[6]=f2bf(f1.z); t.s[7]=f2bf(f1.w);
        *(uint4*)&xbf[base] = t.v;
        return;
    }
    __shared__ u16 tile[32][33];
    const float* in; u16* outp; int N, bx, by;
    if (bid < 3072 + 1728) { int t = bid - 3072; in = wq; outp = wtq; N = 2304; bx = t % 72; by = t / 72; }
    else                   { int t = bid - 4800; in = wo; outp = wto; N = 768;  bx = t % 24; by = t / 24; }
    int n0 = bx * 32, k0 = by * 32;
    int tx = threadIdx.x & 31, ty = threadIdx.x >> 5;
    #pragma unroll
    for (int r = ty; r < 32; r += 8)
        tile[r][tx] = f2bf(in[(size_t)(k0 + r) * N + n0 + tx]);
    __syncthreads();
    #pragma unroll
    for (int r = ty; r < 32; r += 8)
        outp[(size_t)(n0 + r) * 768 + k0 + tx] = tile[tx][r];
}

// -------- QKV GEMM, BK=64, XCD-pinned m-slabs, full-line LDS epilogue --------
// A bf16 [8192][768], Bt bf16 [2304][768]
// Q (*0.125*log2e) -> [b,h,n,64]; K -> [b,h,n,64]; V -> TRANSPOSED [b,h,d,n]
__global__ __launch_bounds__(256) void gemm_qkv(
    const u16* __restrict__ A, const u16* __restrict__ Bt,
    u16* __restrict__ q_out, u16* __restrict__ k_out, u16* __restrict__ v_out)
{
    const int K = 768;
    __shared__ __align__(16) u16 As[128 * 64];   // slot s of row R holds k-group s^(R&7)
    __shared__ __align__(16) u16 Bs[128 * 64];

    int tid = threadIdx.x;
    int lane = tid & 63, wave = tid >> 6;
    int quad = lane >> 4, l16 = lane & 15;
    int wm = wave >> 1, wn = wave & 1;
    // XCD-pinned swizzle (wg->XCD assumed id%8): A m-slab owned by one XCD
    int id = blockIdx.x;
    int xcd = id & 7, j = id >> 3;
    int m0 = (((j & 7) << 3) + xcd) * 128;   // 64 m-tiles
    int n0 = (j >> 3) * 128;                  // 18 n-tiles

    f32x4 acc[4][4];
    #pragma unroll
    for (int i = 0; i < 4; i++)
        #pragma unroll
        for (int jj = 0; jj < 4; jj++) acc[i][jj] = (f32x4){0.f, 0.f, 0.f, 0.f};

    int r0 = tid >> 3, cg = tid & 7;
    for (int kt = 0; kt < K; kt += 64) {
        #pragma unroll
        for (int it = 0; it < 4; ++it) {
            int row = it * 32 + r0;
            int g = cg ^ (row & 7);
            cp16(&A [(size_t)(m0 + row) * K + kt + g * 8], &As[(size_t)(it * 256 + tid) * 8]);
            cp16(&Bt[(size_t)(n0 + row) * K + kt + g * 8], &Bs[(size_t)(it * 256 + tid) * 8]);
        }
        __syncthreads();
        #pragma unroll
        for (int ko = 0; ko < 2; ko++) {
            bf16x8 af[4], bfr[4];
            #pragma unroll
            for (int i = 0; i < 4; i++) {
                int R = wm * 64 + i * 16 + l16;
                af[i] = *(const bf16x8*)&As[R * 64 + (((ko * 4 + quad) ^ (R & 7)) * 8)];
            }
            #pragma unroll
            for (int jj = 0; jj < 4; jj++) {
                int R = wn * 64 + jj * 16 + l16;
                bfr[jj] = *(const bf16x8*)&Bs[R * 64 + (((ko * 4 + quad) ^ (R & 7)) * 8)];
            }
            #pragma unroll
            for (int i = 0; i < 4; i++)
                #pragma unroll
                for (int jj = 0; jj < 4; jj++)
                    acc[i][jj] = __builtin_amdgcn_mfma_f32_16x16x32_bf16(af[i], bfr[jj], acc[i][jj], 0, 0, 0);
        }
        __syncthreads();
    }

    // ---- epilogue: wave tile = 64 m x 64 n, one (part,h); round-trip via LDS ----
    int M0 = m0 + wm * 64, N0 = n0 + wn * 64;
    int part = N0 >= 1536 ? 2 : (N0 >= 768 ? 1 : 0);
    int h = (N0 - part * 768) >> 6;
    int b = M0 >> 10, npos0 = M0 & 1023;
    u16* ep = (wave < 2 ? As : Bs) + (wave & 1) * 4096;   // 8 KB per wave

    if (part != 2) {
        float scale = (part == 0) ? 0.18033688011112042f : 1.0f;   // /8 * log2e for Q
        u16* gbase = (part == 0 ? q_out : k_out) + (((size_t)(b * 12 + h) * 1024 + npos0) << 6);
        #pragma unroll
        for (int i = 0; i < 4; i++)
            #pragma unroll
            for (int jj = 0; jj < 4; jj++) {
                int dd = jj * 16 + l16;
                #pragma unroll
                for (int r = 0; r < 4; r++) {
                    int np = i * 16 + quad * 4 + r;
                    ep[np * 64 + (((dd >> 3) ^ (np & 7)) * 8) + (dd & 7)] =
                        f2bf(acc[i][jj][r] * scale);
                }
            }
        __syncthreads();
        #pragma unroll
        for (int t = 0; t < 8; t++) {
            int idx = t * 512 + lane * 8;
            int np = idx >> 6;
            int slot = ((lane & 7) ^ (np & 7));
            uint4 v = *(const uint4*)&ep[np * 64 + slot * 8];
            *(uint4*)&gbase[idx] = v;
        }
    } else {
        #pragma unroll
        for (int i = 0; i < 4; i++)
            #pragma unroll
            for (int jj = 0; jj < 4; jj++) {
                int dd = jj * 16 + l16;
                int npg = i * 2 + (quad >> 1);
                int sub = (quad & 1) * 4;
                union { u16 s[4]; uint2 v; } pk;
                #pragma unroll
                for (int r = 0; r < 4; r++) pk.s[r] = f2bf(acc[i][jj][r]);
                *(uint2*)&ep[dd * 64 + ((npg ^ (dd & 7)) * 8) + sub] = pk.v;
            }
        __syncthreads();
        #pragma unroll
        for (int t = 0; t < 8; t++) {
            int dd = t * 8 + (lane >> 3);
            int npg = lane & 7;
            uint4 v = *(const uint4*)&ep[dd * 64 + ((npg ^ (dd & 7)) * 8)];
            *(uint4*)&v_out[((size_t)((b * 12 + h) * 64 + dd)) * 1024 + npos0 + npg * 8] = v;
        }
    }
}

// -------- attention: S^T form, 128 q/block, XCD-pinned heads --------
__global__ __launch_bounds__(256) void attn128(
    u16* __restrict__ QO, const u16* __restrict__ Kg, const u16* __restrict__ Vtg)
{
    __shared__ __align__(16) u16 Ks[64 * 64];   // [kv][d], 8-elem groups XOR-swizzled
    __shared__ __align__(16) u16 Vs[64 * 64];   // [d][kv], 8-elem groups XOR-swizzled

    int tid = threadIdx.x;
    int lane = tid & 63, wave = tid >> 6;
    int quad = lane >> 4, l16 = lane & 15;
    // XCD-pinned: 12 heads per XCD; the 8 q-blocks of a head stay on its XCD
    int id = blockIdx.x;
    int xcd = id & 7, j = id >> 3;              // j in [0,96)
    int bh = xcd * 12 + (j >> 3);
    int q0 = (j & 7) * 128;
    const size_t head_base = (size_t)bh * 65536;

    size_t qoff[2];
    bf16x8 qf[2][2];
    #pragma unroll
    for (int qs = 0; qs < 2; qs++) {
        qoff[qs] = head_base + (size_t)(q0 + wave * 32 + qs * 16 + l16) * 64;
        qf[qs][0] = *(const bf16x8*)&QO[qoff[qs] + quad * 8];
        qf[qs][1] = *(const bf16x8*)&QO[qoff[qs] + 32 + quad * 8];
    }

    f32x4 Oacc[4][2];
    #pragma unroll
    for (int dt = 0; dt < 4; dt++)
        #pragma unroll
        for (int qs = 0; qs < 2; qs++) Oacc[dt][qs] = (f32x4){0.f, 0.f, 0.f, 0.f};
    float l_part[2] = {0.f, 0.f};

    int srow = tid >> 3, sg = tid & 7;
    for (int j0 = 0; j0 < 1024; j0 += 64) {
        #pragma unroll
        for (int it = 0; it < 2; ++it) {
            int e = it * 256 + tid, row = it * 32 + srow, gs = sg ^ (row & 7);
            cp16(&Kg [head_base + (size_t)(j0 + row) * 64 + gs * 8], &Ks[(size_t)e * 8]);
            cp16(&Vtg[head_base + (size_t)row * 1024 + j0 + gs * 8], &Vs[(size_t)e * 8]);
        }
        __syncthreads();

        f32x4 s4[4][2];
        #pragma unroll
        for (int nt = 0; nt < 4; nt++) {
            int R = nt * 16 + l16;
            bf16x8 kf0 = *(const bf16x8*)&Ks[R * 64 + ((quad       ^ (R & 7)) * 8)];
            bf16x8 kf1 = *(const bf16x8*)&Ks[R * 64 + (((quad + 4) ^ (R & 7)) * 8)];
            #pragma unroll
            for (int qs = 0; qs < 2; qs++) {
                f32x4 s = (f32x4){0.f, 0.f, 0.f, 0.f};
                s = __builtin_amdgcn_mfma_f32_16x16x32_bf16(kf0, qf[qs][0], s, 0, 0, 0);
                s = __builtin_amdgcn_mfma_f32_16x16x32_bf16(kf1, qf[qs][1], s, 0, 0, 0);
                s4[nt][qs] = s;
            }
        }

        // p = 2^s, truncated to bf16; l accumulates the SAME truncated values,
        // so normalization p~/sum(p~) is an exact convex combination.
        u16 ph[4][2][4];
        #pragma unroll
        for (int nt = 0; nt < 4; nt++)
            #pragma unroll
            for (int qs = 0; qs < 2; qs++)
                #pragma unroll
                for (int r = 0; r < 4; r++) {
                    float p = __builtin_amdgcn_exp2f(s4[nt][qs][r]);
                    l_part[qs] += truncbf(p, ph[nt][qs][r]);
                }

        #pragma unroll
        for (int h = 0; h < 2; h++) {
            union { u16 s[8]; bf16x8 v; } pk[2];
            #pragma unroll
            for (int qs = 0; qs < 2; qs++)
                #pragma unroll
                for (int r = 0; r < 4; r++) {
                    pk[qs].s[r]     = ph[2 * h][qs][r];
                    pk[qs].s[4 + r] = ph[2 * h + 1][qs][r];
                }
            int lg0 = 4 * h + (quad >> 1), lg1 = lg0 + 2;
            int off = (quad & 1) * 4;
            #pragma unroll
            for (int dt = 0; dt < 4; dt++) {
                int drow = dt * 16 + l16;
                union { u16 s[8]; bf16x8 v; } vk;
                *(uint2*)&vk.s[0] = *(const uint2*)&Vs[drow * 64 + (lg0 ^ (drow & 7)) * 8 + off];
                *(uint2*)&vk.s[4] = *(const uint2*)&Vs[drow * 64 + (lg1 ^ (drow & 7)) * 8 + off];
                #pragma unroll
                for (int qs = 0; qs < 2; qs++)
                    Oacc[dt][qs] = __builtin_amdgcn_mfma_f32_16x16x32_bf16(vk.v, pk[qs].v, Oacc[dt][qs], 0, 0, 0);
            }
        }
        __syncthreads();
    }

    #pragma unroll
    for (int qs = 0; qs < 2; qs++) {
        float l = l_part[qs];
        l += __shfl_xor(l, 16);
        l += __shfl_xor(l, 32);
        float rl = __builtin_amdgcn_rcpf(l);
        #pragma unroll
        for (int dt = 0; dt < 4; dt++) {
            union { u16 s[4]; uint2 v; } ok;
            #pragma unroll
            for (int r = 0; r < 4; r++) ok.s[r] = f2bf(Oacc[dt][qs][r] * rl);
            *(uint2*)&QO[qoff[qs] + dt * 16 + quad * 4] = ok.v;
        }
    }
}

// -------- out-proj GEMM, BK=64, XCD-pinned m-slabs --------
__global__ __launch_bounds__(256) void gemm_out(
    const u16* __restrict__ Qg, const u16* __restrict__ Bt,
    const float* __restrict__ bias, float* __restrict__ out)
{
    const int K = 768;
    __shared__ __align__(16) u16 As[128 * 64];
    __shared__ __align__(16) u16 Bs[128 * 64];

    int tid = threadIdx.x;
    int lane = tid & 63, wave = tid >> 6;
    int quad = lane >> 4, l16 = lane & 15;
    int wm = wave >> 1, wn = wave & 1;
    int id = blockIdx.x;
    int xcd = id & 7, j = id >> 3;              // j in [0,48)
    int m0 = (((j & 7) << 3) + xcd) * 128;      // 64 m-tiles, XCD-pinned
    int n0 = (j >> 3) * 128;                    // 6 n-tiles

    f32x4 acc[4][4];
    #pragma unroll
    for (int i = 0; i < 4; i++)
        #pragma unroll
        for (int jj = 0; jj < 4; jj++) acc[i][jj] = (f32x4){0.f, 0.f, 0.f, 0.f};

    int r0 = tid >> 3, cg = tid & 7;
    for (int kt = 0; kt < K; kt += 64) {
        int h = kt >> 6;
        #pragma unroll
        for (int it = 0; it < 4; ++it) {
            int row = it * 32 + r0;
            int g = cg ^ (row & 7);
            int m = m0 + row, b = m >> 10, npos = m & 1023;
            cp16(&Qg[(((size_t)(b * 12 + h) * 1024 + npos) << 6) + g * 8],
                 &As[(size_t)(it * 256 + tid) * 8]);
            cp16(&Bt[(size_t)(n0 + row) * K + kt + g * 8],
                 &Bs[(size_t)(it * 256 + tid) * 8]);
        }
        __syncthreads();
        #pragma unroll
        for (int ko = 0; ko < 2; ko++) {
            bf16x8 af[4], bfr[4];
            #pragma unroll
            for (int i = 0; i < 4; i++) {
                int R = wm * 64 + i * 16 + l16;
                af[i] = *(const bf16x8*)&As[R * 64 + (((ko * 4 + quad) ^ (R & 7)) * 8)];
            }
            #pragma unroll
            for (int jj = 0; jj < 4; jj++) {
                int R = wn * 64 + jj * 16 + l16;
                bfr[jj] = *(const bf16x8*)&Bs[R * 64 + (((ko * 4 + quad) ^ (R & 7)) * 8)];
            }
            #pragma unroll
            for (int i = 0; i < 4; i++)
                #pragma unroll
                for (int jj = 0; jj < 4; jj++)
                    acc[i][jj] = __builtin_amdgcn_mfma_f32_16x16x32_bf16(af[i], bfr[jj], acc[i][jj], 0, 0, 0);
        }
        __syncthreads();
    }

    #pragma unroll
    for (int i = 0; i < 4; i++) {
        int mbase = m0 + wm * 64 + i * 16 + quad * 4;
        #pragma unroll
        for (int jj = 0; jj < 4; jj++) {
            int n = n0 + wn * 64 + jj * 16 + l16;
            float bv = bias[n];
            #pragma unroll
            for (int r = 0; r < 4; r++)
                out[(size_t)(mbase + r) * 768 + n] = acc[i][jj][r] + bv;
        }
    }
}

extern "C" void kernel_launch(void* const* d_in, const int* in_sizes, int n_in,
                              void* d_out, int out_size, void* d_ws, size_t ws_size,
                              hipStream_t stream) {
    const float* x     = (const float*)d_in[0];   // [8,1024,768] f32
    const float* w_qkv = (const float*)d_in[1];   // [768,2304] f32
    const float* w_out = (const float*)d_in[2];   // [768,768] f32
    const float* b_out = (const float*)d_in[3];   // [768] f32
    float* out = (float*)d_out;                   // [8,1024,768] f32

    char* ws = (char*)d_ws;
    u16* wtq  = (u16*)(ws);                   // [2304][768] bf16    3,538,944 B
    u16* wto  = (u16*)(ws + 3538944);         // [768][768]  bf16    1,179,648 B
    u16* Qbuf = (u16*)(ws + 4718592);         // [8,12,1024,64] bf16 12,582,912 B
    u16* xbf  = (u16*)(ws + 17301504);        // [8192][768] bf16    12,582,912 B  (29.9 MB)
    // K natural [b,h,n,64] and V TRANSPOSED [b,h,64,n] live in d_out (2x12.58 MB);
    // both fully consumed by attn128 before gemm_out overwrites d_out.
    u16* Kbuf = (u16*)d_out;
    u16* Vbuf = (u16*)d_out + 6291456;

    prep<<<dim3(5376), 256, 0, stream>>>(x, w_qkv, w_out, xbf, wtq, wto);
    gemm_qkv<<<dim3(1152), 256, 0, stream>>>(xbf, wtq, Qbuf, Kbuf, Vbuf);
    attn128<<<dim3(768), 256, 0, stream>>>(Qbuf, Kbuf, Vbuf);
    gemm_out<<<dim3(384), 256, 0, stream>>>(Qbuf, wto, b_out, out);
}

// Round 7
// 183.728 us; speedup vs baseline: 1.6408x; 1.0578x over previous
//
#include <hip/hip_runtime.h>

typedef unsigned short u16;
typedef __bf16 bf16x8 __attribute__((ext_vector_type(8)));
typedef float f32x4 __attribute__((ext_vector_type(4)));

__device__ inline u16 f2bf(float f) {
    union { float f; unsigned int u; } a; a.f = f;
    unsigned int u = a.u + 0x7fffu + ((a.u >> 16) & 1u);
    return (u16)(u >> 16);
}
// truncate f32 -> bf16 bits; returns truncated value as f32
__device__ __forceinline__ float truncbf(float f, u16& h) {
    union { float f; unsigned int u; } a; a.f = f;
    a.u &= 0xffff0000u;
    h = (u16)(a.u >> 16);
    return a.f;
}

// async global->LDS, 16B per lane. LDS side is wave-uniform base + lane*16.
__device__ __forceinline__ void cp16(const void* g, void* l) {
    __builtin_amdgcn_global_load_lds(
        (const __attribute__((address_space(1))) unsigned int*)g,
        (__attribute__((address_space(3))) unsigned int*)l, 16, 0, 0);
}

// -------- prep: fuse x-cast + both weight transposes (1 launch) --------
__global__ __launch_bounds__(256) void prep(
    const float* __restrict__ x, const float* __restrict__ wq,
    const float* __restrict__ wo, u16* __restrict__ xbf,
    u16* __restrict__ wtq, u16* __restrict__ wto)
{
    int bid = blockIdx.x;
    if (bid < 3072) {                      // cast x: f32 -> bf16, 8/thread
        size_t base = ((size_t)bid * 256 + threadIdx.x) * 8;
        float4 f0 = *(const float4*)&x[base];
        float4 f1 = *(const float4*)&x[base + 4];
        union { u16 s[8]; uint4 v; } t;
        t.s[0]=f2bf(f0.x); t.s[1]=f2bf(f0.y); t.s[2]=f2bf(f0.z); t.s[3]=f2bf(f0.w);
        t.s[4]=f2bf(f1.x); t.s[5]=f2bf(f1.y); t.s[6]=f2bf(f1.z); t.s[7]=f2bf(f1.w);
        *(uint4*)&xbf[base] = t.v;
        return;
    }
    __shared__ u16 tile[32][33];
    const float* in; u16* outp; int N, bx, by;
    if (bid < 3072 + 1728) { int t = bid - 3072; in = wq; outp = wtq; N = 2304; bx = t % 72; by = t / 72; }
    else                   { int t = bid - 4800; in = wo; outp = wto; N = 768;  bx = t % 24; by = t / 24; }
    int n0 = bx * 32, k0 = by * 32;
    int tx = threadIdx.x & 31, ty = threadIdx.x >> 5;
    #pragma unroll
    for (int r = ty; r < 32; r += 8)
        tile[r][tx] = f2bf(in[(size_t)(k0 + r) * N + n0 + tx]);
    __syncthreads();
    #pragma unroll
    for (int r = ty; r < 32; r += 8)
        outp[(size_t)(n0 + r) * 768 + k0 + tx] = tile[tx][r];
}

// -------- QKV GEMM: BK=64, dbuf prefetch-ahead, 1 barrier/iter, XCD-pinned --------
// A bf16 [8192][768], Bt bf16 [2304][768]
// Q (*0.125*log2e) -> [b,h,n,64]; K -> [b,h,n,64]; V -> TRANSPOSED [b,h,d,n]
__global__ __launch_bounds__(256) void gemm_qkv(
    const u16* __restrict__ A, const u16* __restrict__ Bt,
    u16* __restrict__ q_out, u16* __restrict__ k_out, u16* __restrict__ v_out)
{
    const int K = 768;
    __shared__ __align__(16) u16 As[2][128 * 64];   // slot s of row R holds k-group s^(R&7)
    __shared__ __align__(16) u16 Bs[2][128 * 64];

    int tid = threadIdx.x;
    int lane = tid & 63, wave = tid >> 6;
    int quad = lane >> 4, l16 = lane & 15;
    int wm = wave >> 1, wn = wave & 1;
    int id = blockIdx.x;
    int xcd = id & 7, j = id >> 3;
    int m0 = (((j & 7) << 3) + xcd) * 128;   // 64 m-tiles, XCD-pinned A slabs
    int n0 = (j >> 3) * 128;                 // 18 n-tiles

    f32x4 acc[4][4];
    #pragma unroll
    for (int i = 0; i < 4; i++)
        #pragma unroll
        for (int jj = 0; jj < 4; jj++) acc[i][jj] = (f32x4){0.f, 0.f, 0.f, 0.f};

    int r0 = tid >> 3, cg = tid & 7;
    int g = cg ^ (r0 & 7);                   // row&7 == r0&7 for all 4 its
    const u16* GA[4]; const u16* GB[4];
    #pragma unroll
    for (int it = 0; it < 4; it++) {
        GA[it] = A  + (size_t)(m0 + it * 32 + r0) * K + g * 8;
        GB[it] = Bt + (size_t)(n0 + it * 32 + r0) * K + g * 8;
    }

    #define STAGE_QKV(kt, b)                                          \
        _Pragma("unroll")                                             \
        for (int it = 0; it < 4; it++) {                              \
            cp16(GA[it] + (kt), &As[b][(it * 256 + tid) * 8]);        \
            cp16(GB[it] + (kt), &Bs[b][(it * 256 + tid) * 8]);        \
        }

    STAGE_QKV(0, 0)
    for (int i = 0; i < 12; i++) {
        int b = i & 1;
        __syncthreads();                     // drains exactly the loads for buf b
        bf16x8 af[2][4], bfr[2][4];          // read fragments BEFORE issuing prefetch
        #pragma unroll
        for (int ko = 0; ko < 2; ko++)
            #pragma unroll
            for (int x = 0; x < 4; x++) {
                int Ra = wm * 64 + x * 16 + l16;
                af[ko][x]  = *(const bf16x8*)&As[b][Ra * 64 + (((ko * 4 + quad) ^ (Ra & 7)) * 8)];
                int Rb = wn * 64 + x * 16 + l16;
                bfr[ko][x] = *(const bf16x8*)&Bs[b][Rb * 64 + (((ko * 4 + quad) ^ (Rb & 7)) * 8)];
            }
        if (i + 1 < 12) { STAGE_QKV((i + 1) * 64, b ^ 1) }   // in flight across MFMAs
        #pragma unroll
        for (int ko = 0; ko < 2; ko++)
            #pragma unroll
            for (int x = 0; x < 4; x++)
                #pragma unroll
                for (int y = 0; y < 4; y++)
                    acc[x][y] = __builtin_amdgcn_mfma_f32_16x16x32_bf16(af[ko][x], bfr[ko][y], acc[x][y], 0, 0, 0);
    }
    #undef STAGE_QKV

    // ---- epilogue: wave tile = 64m x 64n, one (part,h); per-wave LDS region in buf0 ----
    int M0 = m0 + wm * 64, N0 = n0 + wn * 64;
    int part = N0 >= 1536 ? 2 : (N0 >= 768 ? 1 : 0);
    int h = (N0 - part * 768) >> 6;
    int b2 = M0 >> 10, npos0 = M0 & 1023;
    u16* ep = (wave < 2 ? As[0] : Bs[0]) + (wave & 1) * 4096;   // 8 KB per wave (buf0: free)

    if (part != 2) {
        float scale = (part == 0) ? 0.18033688011112042f : 1.0f;   // /8 * log2e for Q
        u16* gbase = (part == 0 ? q_out : k_out) + (((size_t)(b2 * 12 + h) * 1024 + npos0) << 6);
        #pragma unroll
        for (int i = 0; i < 4; i++)
            #pragma unroll
            for (int jj = 0; jj < 4; jj++) {
                int dd = jj * 16 + l16;
                #pragma unroll
                for (int r = 0; r < 4; r++) {
                    int np = i * 16 + quad * 4 + r;
                    ep[np * 64 + (((dd >> 3) ^ (np & 7)) * 8) + (dd & 7)] =
                        f2bf(acc[i][jj][r] * scale);
                }
            }
        #pragma unroll
        for (int t = 0; t < 8; t++) {        // per-wave region: ds order suffices, no barrier
            int idx = t * 512 + lane * 8;
            int np = idx >> 6;
            int slot = ((lane & 7) ^ (np & 7));
            uint4 v = *(const uint4*)&ep[np * 64 + slot * 8];
            *(uint4*)&gbase[idx] = v;
        }
    } else {
        #pragma unroll
        for (int i = 0; i < 4; i++)
            #pragma unroll
            for (int jj = 0; jj < 4; jj++) {
                int dd = jj * 16 + l16;
                int npg = i * 2 + (quad >> 1);
                int sub = (quad & 1) * 4;
                union { u16 s[4]; uint2 v; } pk;
                #pragma unroll
                for (int r = 0; r < 4; r++) pk.s[r] = f2bf(acc[i][jj][r]);
                *(uint2*)&ep[dd * 64 + ((npg ^ (dd & 7)) * 8) + sub] = pk.v;
            }
        #pragma unroll
        for (int t = 0; t < 8; t++) {
            int dd = t * 8 + (lane >> 3);
            int npg = lane & 7;
            uint4 v = *(const uint4*)&ep[dd * 64 + ((npg ^ (dd & 7)) * 8)];
            *(uint4*)&v_out[((size_t)((b2 * 12 + h) * 64 + dd)) * 1024 + npos0 + npg * 8] = v;
        }
    }
}

// -------- attention: S^T form, 128 q/block, dbuf prefetch-ahead, XCD-pinned heads --------
__global__ __launch_bounds__(256) void attn128(
    u16* __restrict__ QO, const u16* __restrict__ Kg, const u16* __restrict__ Vtg)
{
    __shared__ __align__(16) u16 Ks[2][64 * 64];   // [kv][d], groups XOR-swizzled
    __shared__ __align__(16) u16 Vs[2][64 * 64];   // [d][kv], groups XOR-swizzled

    int tid = threadIdx.x;
    int lane = tid & 63, wave = tid >> 6;
    int quad = lane >> 4, l16 = lane & 15;
    int id = blockIdx.x;
    int xcd = id & 7, j = id >> 3;              // 12 heads per XCD
    int bh = xcd * 12 + (j >> 3);
    int q0 = (j & 7) * 128;
    const size_t head_base = (size_t)bh * 65536;

    size_t qoff[2];
    bf16x8 qf[2][2];
    #pragma unroll
    for (int qs = 0; qs < 2; qs++) {
        qoff[qs] = head_base + (size_t)(q0 + wave * 32 + qs * 16 + l16) * 64;
        qf[qs][0] = *(const bf16x8*)&QO[qoff[qs] + quad * 8];
        qf[qs][1] = *(const bf16x8*)&QO[qoff[qs] + 32 + quad * 8];
    }

    f32x4 Oacc[4][2];
    #pragma unroll
    for (int dt = 0; dt < 4; dt++)
        #pragma unroll
        for (int qs = 0; qs < 2; qs++) Oacc[dt][qs] = (f32x4){0.f, 0.f, 0.f, 0.f};
    float l_part[2] = {0.f, 0.f};

    int srow = tid >> 3, sg = tid & 7;
    int gs = sg ^ (srow & 7);
    const u16* GK[2]; const u16* GV[2];
    #pragma unroll
    for (int it = 0; it < 2; it++) {
        GK[it] = Kg  + head_base + (size_t)(it * 32 + srow) * 64 + gs * 8;
        GV[it] = Vtg + head_base + (size_t)(it * 32 + srow) * 1024 + gs * 8;
    }

    #define STAGE_ATT(j0, b)                                          \
        _Pragma("unroll")                                             \
        for (int it = 0; it < 2; it++) {                              \
            cp16(GK[it] + (size_t)(j0) * 64, &Ks[b][(it * 256 + tid) * 8]); \
            cp16(GV[it] + (j0),             &Vs[b][(it * 256 + tid) * 8]); \
        }

    STAGE_ATT(0, 0)
    for (int i = 0; i < 16; i++) {
        int b = i & 1;
        __syncthreads();
        bf16x8 kf[4][2];                      // K fragments first
        #pragma unroll
        for (int nt = 0; nt < 4; nt++) {
            int R = nt * 16 + l16;
            kf[nt][0] = *(const bf16x8*)&Ks[b][R * 64 + ((quad       ^ (R & 7)) * 8)];
            kf[nt][1] = *(const bf16x8*)&Ks[b][R * 64 + (((quad + 4) ^ (R & 7)) * 8)];
        }
        if (i + 1 < 16) { STAGE_ATT((i + 1) * 64, b ^ 1) }

        f32x4 s4[4][2];
        #pragma unroll
        for (int nt = 0; nt < 4; nt++)
            #pragma unroll
            for (int qs = 0; qs < 2; qs++) {
                f32x4 s = (f32x4){0.f, 0.f, 0.f, 0.f};
                s = __builtin_amdgcn_mfma_f32_16x16x32_bf16(kf[nt][0], qf[qs][0], s, 0, 0, 0);
                s = __builtin_amdgcn_mfma_f32_16x16x32_bf16(kf[nt][1], qf[qs][1], s, 0, 0, 0);
                s4[nt][qs] = s;
            }

        // p = 2^s, truncated to bf16; l sums the SAME truncated values
        u16 ph[4][2][4];
        #pragma unroll
        for (int nt = 0; nt < 4; nt++)
            #pragma unroll
            for (int qs = 0; qs < 2; qs++)
                #pragma unroll
                for (int r = 0; r < 4; r++) {
                    float p = __builtin_amdgcn_exp2f(s4[nt][qs][r]);
                    l_part[qs] += truncbf(p, ph[nt][qs][r]);
                }

        #pragma unroll
        for (int h = 0; h < 2; h++) {
            union { u16 s[8]; bf16x8 v; } pk[2];
            #pragma unroll
            for (int qs = 0; qs < 2; qs++)
                #pragma unroll
                for (int r = 0; r < 4; r++) {
                    pk[qs].s[r]     = ph[2 * h][qs][r];
                    pk[qs].s[4 + r] = ph[2 * h + 1][qs][r];
                }
            int lg0 = 4 * h + (quad >> 1), lg1 = lg0 + 2;
            int off = (quad & 1) * 4;
            #pragma unroll
            for (int dt = 0; dt < 4; dt++) {
                int drow = dt * 16 + l16;
                union { u16 s[8]; bf16x8 v; } vk;
                *(uint2*)&vk.s[0] = *(const uint2*)&Vs[b][drow * 64 + (lg0 ^ (drow & 7)) * 8 + off];
                *(uint2*)&vk.s[4] = *(const uint2*)&Vs[b][drow * 64 + (lg1 ^ (drow & 7)) * 8 + off];
                #pragma unroll
                for (int qs = 0; qs < 2; qs++)
                    Oacc[dt][qs] = __builtin_amdgcn_mfma_f32_16x16x32_bf16(vk.v, pk[qs].v, Oacc[dt][qs], 0, 0, 0);
            }
        }
    }
    #undef STAGE_ATT

    #pragma unroll
    for (int qs = 0; qs < 2; qs++) {
        float l = l_part[qs];
        l += __shfl_xor(l, 16);
        l += __shfl_xor(l, 32);
        float rl = __builtin_amdgcn_rcpf(l);
        #pragma unroll
        for (int dt = 0; dt < 4; dt++) {
            union { u16 s[4]; uint2 v; } ok;
            #pragma unroll
            for (int r = 0; r < 4; r++) ok.s[r] = f2bf(Oacc[dt][qs][r] * rl);
            *(uint2*)&QO[qoff[qs] + dt * 16 + quad * 4] = ok.v;
        }
    }
}

// -------- out-proj GEMM: BK=64, dbuf prefetch-ahead, XCD-pinned --------
__global__ __launch_bounds__(256) void gemm_out(
    const u16* __restrict__ Qg, const u16* __restrict__ Bt,
    const float* __restrict__ bias, float* __restrict__ out)
{
    const int K = 768;
    __shared__ __align__(16) u16 As[2][128 * 64];
    __shared__ __align__(16) u16 Bs[2][128 * 64];

    int tid = threadIdx.x;
    int lane = tid & 63, wave = tid >> 6;
    int quad = lane >> 4, l16 = lane & 15;
    int wm = wave >> 1, wn = wave & 1;
    int id = blockIdx.x;
    int xcd = id & 7, j = id >> 3;
    int m0 = (((j & 7) << 3) + xcd) * 128;
    int n0 = (j >> 3) * 128;

    f32x4 acc[4][4];
    #pragma unroll
    for (int i = 0; i < 4; i++)
        #pragma unroll
        for (int jj = 0; jj < 4; jj++) acc[i][jj] = (f32x4){0.f, 0.f, 0.f, 0.f};

    int r0 = tid >> 3, cg = tid & 7;
    int g = cg ^ (r0 & 7);
    const u16* GA[4]; const u16* GB[4];
    #pragma unroll
    for (int it = 0; it < 4; it++) {
        int m = m0 + it * 32 + r0, b = m >> 10, npos = m & 1023;
        GA[it] = Qg + (((size_t)(b * 12) * 1024 + npos) << 6) + g * 8;  // + h*65536
        GB[it] = Bt + (size_t)(n0 + it * 32 + r0) * K + g * 8;          // + kt
    }

    #define STAGE_OUT(i2, b)                                              \
        _Pragma("unroll")                                                 \
        for (int it = 0; it < 4; it++) {                                  \
            cp16(GA[it] + (size_t)(i2) * 65536, &As[b][(it * 256 + tid) * 8]); \
            cp16(GB[it] + (i2) * 64,            &Bs[b][(it * 256 + tid) * 8]); \
        }

    STAGE_OUT(0, 0)
    for (int i = 0; i < 12; i++) {
        int b = i & 1;
        __syncthreads();
        bf16x8 af[2][4], bfr[2][4];
        #pragma unroll
        for (int ko = 0; ko < 2; ko++)
            #pragma unroll
            for (int x = 0; x < 4; x++) {
                int Ra = wm * 64 + x * 16 + l16;
                af[ko][x]  = *(const bf16x8*)&As[b][Ra * 64 + (((ko * 4 + quad) ^ (Ra & 7)) * 8)];
                int Rb = wn * 64 + x * 16 + l16;
                bfr[ko][x] = *(const bf16x8*)&Bs[b][Rb * 64 + (((ko * 4 + quad) ^ (Rb & 7)) * 8)];
            }
        if (i + 1 < 12) { STAGE_OUT(i + 1, b ^ 1) }
        #pragma unroll
        for (int ko = 0; ko < 2; ko++)
            #pragma unroll
            for (int x = 0; x < 4; x++)
                #pragma unroll
                for (int y = 0; y < 4; y++)
                    acc[x][y] = __builtin_amdgcn_mfma_f32_16x16x32_bf16(af[ko][x], bfr[ko][y], acc[x][y], 0, 0, 0);
    }
    #undef STAGE_OUT

    #pragma unroll
    for (int i = 0; i < 4; i++) {
        int mbase = m0 + wm * 64 + i * 16 + quad * 4;
        #pragma unroll
        for (int jj = 0; jj < 4; jj++) {
            int n = n0 + wn * 64 + jj * 16 + l16;
            float bv = bias[n];
            #pragma unroll
            for (int r = 0; r < 4; r++)
                out[(size_t)(mbase + r) * 768 + n] = acc[i][jj][r] + bv;
        }
    }
}

extern "C" void kernel_launch(void* const* d_in, const int* in_sizes, int n_in,
                              void* d_out, int out_size, void* d_ws, size_t ws_size,
                              hipStream_t stream) {
    const float* x     = (const float*)d_in[0];   // [8,1024,768] f32
    const float* w_qkv = (const float*)d_in[1];   // [768,2304] f32
    const float* w_out = (const float*)d_in[2];   // [768,768] f32
    const float* b_out = (const float*)d_in[3];   // [768] f32
    float* out = (float*)d_out;                   // [8,1024,768] f32

    char* ws = (char*)d_ws;
    u16* wtq  = (u16*)(ws);                   // [2304][768] bf16    3,538,944 B
    u16* wto  = (u16*)(ws + 3538944);         // [768][768]  bf16    1,179,648 B
    u16* Qbuf = (u16*)(ws + 4718592);         // [8,12,1024,64] bf16 12,582,912 B
    u16* xbf  = (u16*)(ws + 17301504);        // [8192][768] bf16    12,582,912 B  (29.9 MB)
    // K natural [b,h,n,64] and V TRANSPOSED [b,h,64,n] live in d_out (2x12.58 MB);
    // both fully consumed by attn128 before gemm_out overwrites d_out.
    u16* Kbuf = (u16*)d_out;
    u16* Vbuf = (u16*)d_out + 6291456;

    prep<<<dim3(5376), 256, 0, stream>>>(x, w_qkv, w_out, xbf, wtq, wto);
    gemm_qkv<<<dim3(1152), 256, 0, stream>>>(xbf, wtq, Qbuf, Kbuf, Vbuf);
    attn128<<<dim3(768), 256, 0, stream>>>(Qbuf, Kbuf, Vbuf);
    gemm_out<<<dim3(384), 256, 0, stream>>>(Qbuf, wto, b_out, out);
}